// Round 1
// baseline (36608.850 us; speedup 1.0000x reference)
//
#include <hip/hip_runtime.h>

typedef __attribute__((ext_vector_type(4))) float f32x4;
typedef __attribute__((ext_vector_type(8))) __bf16 bf16x8;
typedef __attribute__((ext_vector_type(4))) unsigned short u16x4;

#define SCAN_WGS 64
#define GPAD 40   // LDS row pad (ushorts): 80B stride -> 16B aligned, 2-way max bank conflict

// ---------------- persistent scratch (module-scope device memory; avoids d_ws sizing risk) ----
__device__ float    g_h[1024];
__device__ float    g_rh[1024];
__device__ unsigned g_cnt;
__device__ unsigned g_gen;
__device__ float    g_ExW[1024 * 3072];   // [step][z|r|w]
__device__ float    g_hs1[1024 * 1024];
__device__ float    g_hs2[1024 * 1024];

__device__ __forceinline__ unsigned short f2bf(float x) {
  unsigned u = __builtin_bit_cast(unsigned, x);
  u += 0x7FFFu + ((u >> 16) & 1u);   // RNE
  return (unsigned short)(u >> 16);
}

// ---------------- init ----------------
__global__ void init_kernel() {
  int t = threadIdx.x;
  if (t < 1024) { g_h[t] = 0.f; g_rh[t] = 0.f; }
  if (t == 0) { g_cnt = 0u; g_gen = 0u; }
}

// ---------------- device-scope barrier for the persistent scan ----------------
__device__ __forceinline__ void gbar() {
  __syncthreads();
  if (threadIdx.x == 0) {
    __threadfence();   // release: flush this XCD's dirty lines (wbl2)
    unsigned g = __hip_atomic_load(&g_gen, __ATOMIC_RELAXED, __HIP_MEMORY_SCOPE_AGENT);
    unsigned a = __hip_atomic_fetch_add(&g_cnt, 1u, __ATOMIC_ACQ_REL, __HIP_MEMORY_SCOPE_AGENT);
    if (a == (unsigned)(SCAN_WGS - 1)) {
      __hip_atomic_store(&g_cnt, 0u, __ATOMIC_RELAXED, __HIP_MEMORY_SCOPE_AGENT);
      __hip_atomic_store(&g_gen, g + 1u, __ATOMIC_RELEASE, __HIP_MEMORY_SCOPE_AGENT);
    } else {
      while (__hip_atomic_load(&g_gen, __ATOMIC_ACQUIRE, __HIP_MEMORY_SCOPE_AGENT) == g)
        __builtin_amdgcn_s_sleep(1);
    }
    __threadfence();   // acquire: invalidate L1/L2 so h/rh reads are fresh
  }
  __syncthreads();
}

// ---------------- persistent GRU layer scan ----------------
// 64 WGs x 1024 thr. Wave w of WG g owns output column j = g*16+w.
// Phase A: lanes 0-31 dot h*Uz[:,j], lanes 32-63 dot h*Ur[:,j] (32 elems/lane, in regs).
// Phase B: all 64 lanes dot rh*Uw[:,j] (16 elems/lane, in regs).
__global__ __launch_bounds__(1024, 1) void scan_layer(
    const float* __restrict__ ExW,   // [1024][3072] precomputed input terms (z|r|w)
    const float* __restrict__ Uz, const float* __restrict__ Ur, const float* __restrict__ Uw,
    const float* __restrict__ bU,
    float* __restrict__ hs_out)      // [1024][1024]
{
  const int g = blockIdx.x, tid = threadIdx.x;
  const int wave = tid >> 6, lane = tid & 63;
  const int j = g * 16 + wave;
  const int lm = lane & 31;
  __shared__ float h_s[1024];
  __shared__ float rh_s[1024];

  const float* Um = (lane < 32) ? Uz : Ur;
  float u[32], u1[16];
#pragma unroll
  for (int i = 0; i < 32; ++i) u[i] = Um[(size_t)(i * 32 + lm) * 1024 + j];
#pragma unroll
  for (int i = 0; i < 16; ++i) u1[i] = Uw[(size_t)(i * 64 + lane) * 1024 + j];
  const float bu = bU[j];

  float zreg = 0.f;
  for (int s = 0; s < 1024; ++s) {
    // broadcast h into LDS (coalesced)
    h_s[tid] = g_h[tid];
    __syncthreads();
    float acc = 0.f;
#pragma unroll
    for (int i = 0; i < 32; ++i) acc += u[i] * h_s[i * 32 + lm];
#pragma unroll
    for (int off = 16; off >= 1; off >>= 1) acc += __shfl_xor(acc, off, 64);
    if (lane == 0) {
      float x = acc + ExW[s * 3072 + j];
      zreg = 1.f / (1.f + __expf(-x));
    } else if (lane == 32) {
      float x = acc + ExW[s * 3072 + 1024 + j];
      float r = 1.f / (1.f + __expf(-x));
      g_rh[j] = r * h_s[j];
    }
    gbar();
    rh_s[tid] = g_rh[tid];
    __syncthreads();
    float acc2 = 0.f;
#pragma unroll
    for (int i = 0; i < 16; ++i) acc2 += u1[i] * rh_s[i * 64 + lane];
#pragma unroll
    for (int off = 32; off >= 1; off >>= 1) acc2 += __shfl_xor(acc2, off, 64);
    if (lane == 0) {
      float ht = tanhf(acc2 + ExW[s * 3072 + 2048 + j] + bu);
      float hold = h_s[j];
      float hn = zreg * ht + (1.f - zreg) * hold;
      g_h[j] = hn;
      hs_out[(size_t)s * 1024 + j] = hn;
    }
    gbar();
  }
}

// ---------------- bf16 MFMA GEMM: C[M=1024][N] = A(f32,[gather])*B(f32) + bias ----------------
// Block 128x128, 4 waves (2x2), wave = 64x64 via 4x4 of 16x16x32 bf16 MFMA. fp32 inputs cast
// to bf16 during LDS staging; fp32 accumulate.
__global__ __launch_bounds__(256, 1) void gemm_mfma(
    const float* __restrict__ A, const int* __restrict__ gidx, int lda,
    const float* __restrict__ B, int ldb,
    const float* __restrict__ bias,
    float* __restrict__ C, int ldc, int N, int K)
{
  __shared__ unsigned short As[128 * GPAD];
  __shared__ unsigned short Bs[128 * GPAD];
  const int tid = threadIdx.x;
  const int lane = tid & 63;
  const int wv = tid >> 6;
  const int wm = wv >> 1, wn = wv & 1;
  const int mbase = blockIdx.y * 128, nbase = blockIdx.x * 128;

  f32x4 acc[4][4];
#pragma unroll
  for (int i = 0; i < 4; ++i)
#pragma unroll
    for (int q = 0; q < 4; ++q) acc[i][q] = (f32x4){0.f, 0.f, 0.f, 0.f};

  const int ar = tid >> 1, ak = (tid & 1) * 16;
  const float* Arow;
  {
    int m = mbase + ar;
    long long gr = gidx ? (long long)gidx[m] : (long long)m;
    Arow = A + (size_t)gr * (size_t)lda;
  }
  const int bn = (tid >> 3) * 4;   // 0..124
  const int bk = (tid & 7) * 4;    // 0..28
  const bool nedge = (nbase + 128 > N);

  const int ksteps = (K + 31) >> 5;
  for (int ks = 0; ks < ksteps; ++ks) {
    const int k0 = ks << 5;
    __syncthreads();
    // stage A: 128 rows x 32 k
    {
      float v[16];
      const int kg = k0 + ak;
      if (kg + 16 <= K) {
#pragma unroll
        for (int q = 0; q < 4; ++q) {
          f32x4 t = *(const f32x4*)(Arow + kg + q * 4);
          v[q * 4 + 0] = t.x; v[q * 4 + 1] = t.y; v[q * 4 + 2] = t.z; v[q * 4 + 3] = t.w;
        }
      } else {
#pragma unroll
        for (int i = 0; i < 16; ++i) v[i] = (kg + i < K) ? Arow[kg + i] : 0.f;
      }
#pragma unroll
      for (int q = 0; q < 4; ++q) {
        u16x4 w;
        w.x = f2bf(v[q * 4 + 0]); w.y = f2bf(v[q * 4 + 1]);
        w.z = f2bf(v[q * 4 + 2]); w.w = f2bf(v[q * 4 + 3]);
        *(u16x4*)&As[ar * GPAD + ak + q * 4] = w;
      }
    }
    // stage B: 32 k x 128 n, transposed into Bs[n][k]
    {
      float bv[4][4];
#pragma unroll
      for (int kk = 0; kk < 4; ++kk) {
        int kglob = k0 + bk + kk;
        if (kglob < K) {
          if (!nedge) {
            f32x4 t = *(const f32x4*)(B + (size_t)kglob * (size_t)ldb + nbase + bn);
            bv[kk][0] = t.x; bv[kk][1] = t.y; bv[kk][2] = t.z; bv[kk][3] = t.w;
          } else {
#pragma unroll
            for (int nn = 0; nn < 4; ++nn) {
              int n = nbase + bn + nn;
              bv[kk][nn] = (n < N) ? B[(size_t)kglob * (size_t)ldb + n] : 0.f;
            }
          }
        } else {
          bv[kk][0] = bv[kk][1] = bv[kk][2] = bv[kk][3] = 0.f;
        }
      }
#pragma unroll
      for (int nn = 0; nn < 4; ++nn) {
        u16x4 w;
        w.x = f2bf(bv[0][nn]); w.y = f2bf(bv[1][nn]);
        w.z = f2bf(bv[2][nn]); w.w = f2bf(bv[3][nn]);
        *(u16x4*)&Bs[(bn + nn) * GPAD + bk] = w;
      }
    }
    __syncthreads();
    // MFMA: A frag row=lane&15, k=(lane>>4)*8+e ; B frag col=lane&15, k=(lane>>4)*8+e
    bf16x8 af[4], bfr[4];
    const int fr = lane & 15, fk = (lane >> 4) * 8;
#pragma unroll
    for (int mf = 0; mf < 4; ++mf)
      af[mf] = *(const bf16x8*)&As[(wm * 64 + mf * 16 + fr) * GPAD + fk];
#pragma unroll
    for (int nf = 0; nf < 4; ++nf)
      bfr[nf] = *(const bf16x8*)&Bs[(wn * 64 + nf * 16 + fr) * GPAD + fk];
#pragma unroll
    for (int mf = 0; mf < 4; ++mf)
#pragma unroll
      for (int nf = 0; nf < 4; ++nf)
        acc[mf][nf] = __builtin_amdgcn_mfma_f32_16x16x32_bf16(af[mf], bfr[nf], acc[mf][nf], 0, 0, 0);
  }
  // epilogue: C/D layout col=lane&15, row=(lane>>4)*4+reg
  const int fr = lane & 15, fq = lane >> 4;
#pragma unroll
  for (int nf = 0; nf < 4; ++nf) {
    int col = nbase + wn * 64 + nf * 16 + fr;
    if (col < N) {
      float bb = bias ? bias[col] : 0.f;
#pragma unroll
      for (int mf = 0; mf < 4; ++mf) {
        int row0 = mbase + wm * 64 + mf * 16 + fq * 4;
#pragma unroll
        for (int r = 0; r < 4; ++r)
          C[(size_t)(row0 + r) * (size_t)ldc + col] = acc[mf][nf][r] + bb;
      }
    }
  }
}

// ---------------- row-wise log-softmax, in place on d_out ----------------
__global__ __launch_bounds__(256, 1) void logsoftmax_kernel(float* __restrict__ out) {
  const int row = blockIdx.x;
  float* p; int len;
  if (row < 1024) { p = out + (size_t)row * 50000u; len = 50000; }
  else            { p = out + 51200000ull + (size_t)(row - 1024) * 25000u; len = 25000; }
  const int tid = threadIdx.x;
  __shared__ float mred[4], sred[4];

  float m = -3.4e38f;
  for (int i = tid * 4; i < len; i += 1024) {
    f32x4 v = *(const f32x4*)(p + i);
    m = fmaxf(m, fmaxf(fmaxf(v.x, v.y), fmaxf(v.z, v.w)));
  }
#pragma unroll
  for (int off = 32; off >= 1; off >>= 1) m = fmaxf(m, __shfl_xor(m, off, 64));
  if ((tid & 63) == 0) mred[tid >> 6] = m;
  __syncthreads();
  m = fmaxf(fmaxf(mred[0], mred[1]), fmaxf(mred[2], mred[3]));

  float ssum = 0.f;
  for (int i = tid * 4; i < len; i += 1024) {
    f32x4 v = *(const f32x4*)(p + i);
    ssum += __expf(v.x - m) + __expf(v.y - m) + __expf(v.z - m) + __expf(v.w - m);
  }
#pragma unroll
  for (int off = 32; off >= 1; off >>= 1) ssum += __shfl_xor(ssum, off, 64);
  if ((tid & 63) == 0) sred[tid >> 6] = ssum;
  __syncthreads();
  const float lse = m + logf(sred[0] + sred[1] + sred[2] + sred[3]);

  for (int i = tid * 4; i < len; i += 1024) {
    f32x4 v = *(const f32x4*)(p + i);
    v.x -= lse; v.y -= lse; v.z -= lse; v.w -= lse;
    *(f32x4*)(p + i) = v;
  }
}

// ---------------- launch ----------------
extern "C" void kernel_launch(void* const* d_in, const int* in_sizes, int n_in,
                              void* d_out, int out_size, void* d_ws, size_t ws_size,
                              hipStream_t stream) {
  (void)in_sizes; (void)n_in; (void)out_size; (void)d_ws; (void)ws_size;
  const int*   x_idx = (const int*)  d_in[0];
  const float* X     = (const float*)d_in[1];
  const float* W_z_1 = (const float*)d_in[2];
  const float* U_z_1 = (const float*)d_in[3];
  const float* W_r_1 = (const float*)d_in[4];
  const float* U_r_1 = (const float*)d_in[5];
  const float* W_1   = (const float*)d_in[6];
  const float* b_W_1 = (const float*)d_in[7];
  const float* U_1   = (const float*)d_in[8];
  const float* b_U_1 = (const float*)d_in[9];
  const float* W_z_2 = (const float*)d_in[10];
  const float* U_z_2 = (const float*)d_in[11];
  const float* W_r_2 = (const float*)d_in[12];
  const float* U_r_2 = (const float*)d_in[13];
  const float* W_2   = (const float*)d_in[14];
  const float* b_W_2 = (const float*)d_in[15];
  const float* U_2   = (const float*)d_in[16];
  const float* b_U_2 = (const float*)d_in[17];
  const float* W_g   = (const float*)d_in[18];
  const float* b_g   = (const float*)d_in[19];
  const float* W_s   = (const float*)d_in[20];
  const float* b_s   = (const float*)d_in[21];
  float* out = (float*)d_out;

  float *ExW, *hs1, *hs2;
  hipGetSymbolAddress((void**)&ExW, HIP_SYMBOL(g_ExW));
  hipGetSymbolAddress((void**)&hs1, HIP_SYMBOL(g_hs1));
  hipGetSymbolAddress((void**)&hs2, HIP_SYMBOL(g_hs2));

  const dim3 blk(256);

  // layer-1 input projections: E(=X[idx]) @ {W_z_1, W_r_1, W_1}  -> g_ExW
  init_kernel<<<dim3(1), dim3(1024), 0, stream>>>();
  gemm_mfma<<<dim3(8, 8), blk, 0, stream>>>(X, x_idx, 300, W_z_1, 1024, nullptr, ExW + 0,    3072, 1024, 300);
  gemm_mfma<<<dim3(8, 8), blk, 0, stream>>>(X, x_idx, 300, W_r_1, 1024, nullptr, ExW + 1024, 3072, 1024, 300);
  gemm_mfma<<<dim3(8, 8), blk, 0, stream>>>(X, x_idx, 300, W_1,   1024, b_W_1,   ExW + 2048, 3072, 1024, 300);
  // layer-1 scan
  scan_layer<<<dim3(SCAN_WGS), dim3(1024), 0, stream>>>(ExW, U_z_1, U_r_1, U_1, b_U_1, hs1);
  // layer-2 input projections: h1 @ {W_z_2, W_r_2, W_2} -> g_ExW (reuse)
  init_kernel<<<dim3(1), dim3(1024), 0, stream>>>();
  gemm_mfma<<<dim3(8, 8), blk, 0, stream>>>(hs1, nullptr, 1024, W_z_2, 1024, nullptr, ExW + 0,    3072, 1024, 1024);
  gemm_mfma<<<dim3(8, 8), blk, 0, stream>>>(hs1, nullptr, 1024, W_r_2, 1024, nullptr, ExW + 1024, 3072, 1024, 1024);
  gemm_mfma<<<dim3(8, 8), blk, 0, stream>>>(hs1, nullptr, 1024, W_2,   1024, b_W_2,   ExW + 2048, 3072, 1024, 1024);
  // layer-2 scan
  scan_layer<<<dim3(SCAN_WGS), dim3(1024), 0, stream>>>(ExW, U_z_2, U_r_2, U_2, b_U_2, hs2);
  // heads: logits straight into d_out
  gemm_mfma<<<dim3(391, 8), blk, 0, stream>>>(hs2, nullptr, 1024, W_g, 50000, b_g, out,              50000, 50000, 1024);
  gemm_mfma<<<dim3(196, 8), blk, 0, stream>>>(hs2, nullptr, 1024, W_s, 25000, b_s, out + 51200000ll, 25000, 25000, 1024);
  // in-place log-softmax
  logsoftmax_kernel<<<dim3(2048), blk, 0, stream>>>(out);
}

// Round 2
// 16605.669 us; speedup vs baseline: 2.2046x; 2.2046x over previous
//
#include <hip/hip_runtime.h>

typedef __attribute__((ext_vector_type(4))) float f32x4;
typedef __attribute__((ext_vector_type(8))) __bf16 bf16x8;
typedef __attribute__((ext_vector_type(4))) unsigned short u16x4;

#define SCAN_WGS 64
#define GPAD 40   // LDS row pad (ushorts): 80B stride -> 16B aligned, 2-way max bank conflict

// ---------------- persistent scratch (module-scope device memory) ----------------
// h / rh are communicated as tagged 64-bit words: (step_tag << 32) | f32 bits.
// Agent-scope relaxed atomics bypass the non-coherent per-XCD L2s (sc0 sc1) and
// are device-coherent at L3 -- no fences, no L2 writeback/invalidate.
__device__ unsigned long long g_h64[1024];
__device__ unsigned long long g_rh64[1024];
__device__ float    g_ExW[1024 * 3072];   // [step][z|r|w]
__device__ float    g_hs1[1024 * 1024];
__device__ float    g_hs2[1024 * 1024];

__device__ __forceinline__ unsigned short f2bf(float x) {
  unsigned u = __builtin_bit_cast(unsigned, x);
  u += 0x7FFFu + ((u >> 16) & 1u);   // RNE
  return (unsigned short)(u >> 16);
}

__device__ __forceinline__ unsigned long long packtv(unsigned tag, float v) {
  return ((unsigned long long)tag << 32) | (unsigned long long)__builtin_bit_cast(unsigned, v);
}

// ---------------- init: zero state, tag = 0 ----------------
__global__ void init_kernel() {
  int t = threadIdx.x;
  __hip_atomic_store(&g_h64[t],  0ull, __ATOMIC_RELAXED, __HIP_MEMORY_SCOPE_AGENT);
  __hip_atomic_store(&g_rh64[t], 0ull, __ATOMIC_RELAXED, __HIP_MEMORY_SCOPE_AGENT);
}

// ---------------- persistent GRU layer scan (fence-free tagged dataflow) ----------------
// 64 WGs x 1024 thr. Wave w of WG g owns output column j = g*16+w.
// Phase A: lanes 0-31 dot h*Uz[:,j], lanes 32-63 dot h*Ur[:,j] (32 elems/lane, in regs);
//          lane 32 publishes rh_j = r_j * h_j tagged s+1.
// Phase B: all 64 lanes dot rh*Uw[:,j] (16 elems/lane, in regs);
//          lane 0 publishes h_j tagged s+1 and stores hs_out[s][j].
__global__ __launch_bounds__(1024, 1) void scan_layer(
    const float* __restrict__ ExW,   // [1024][3072] precomputed input terms (z|r|w)
    const float* __restrict__ Uz, const float* __restrict__ Ur, const float* __restrict__ Uw,
    const float* __restrict__ bU,
    float* __restrict__ hs_out)      // [1024][1024]
{
  const int g = blockIdx.x, tid = threadIdx.x;
  const int wave = tid >> 6, lane = tid & 63;
  const int j = g * 16 + wave;
  const int lm = lane & 31;
  __shared__ float h_s[1024];
  __shared__ float rh_s[1024];

  const float* Um = (lane < 32) ? Uz : Ur;
  float u[32], u1[16];
#pragma unroll
  for (int i = 0; i < 32; ++i) u[i] = Um[(size_t)(i * 32 + lm) * 1024 + j];
#pragma unroll
  for (int i = 0; i < 16; ++i) u1[i] = Uw[(size_t)(i * 64 + lane) * 1024 + j];
  const float bu = bU[j];

  float zreg = 0.f;
  for (int s = 0; s < 1024; ++s) {
    // ---- phase A: wait for h tagged s (h_{s-1}); stage own element to LDS ----
    {
      unsigned long long pk;
      for (;;) {
        pk = __hip_atomic_load(&g_h64[tid], __ATOMIC_RELAXED, __HIP_MEMORY_SCOPE_AGENT);
        if ((unsigned)(pk >> 32) == (unsigned)s) break;
      }
      h_s[tid] = __builtin_bit_cast(float, (unsigned)pk);
    }
    __syncthreads();
    float acc = 0.f;
#pragma unroll
    for (int i = 0; i < 32; ++i) acc += u[i] * h_s[i * 32 + lm];
#pragma unroll
    for (int off = 16; off >= 1; off >>= 1) acc += __shfl_xor(acc, off, 64);
    if (lane == 0) {
      float x = acc + ExW[s * 3072 + j];
      zreg = 1.f / (1.f + __expf(-x));
    } else if (lane == 32) {
      float x = acc + ExW[s * 3072 + 1024 + j];
      float r = 1.f / (1.f + __expf(-x));
      __hip_atomic_store(&g_rh64[j], packtv((unsigned)(s + 1), r * h_s[j]),
                         __ATOMIC_RELAXED, __HIP_MEMORY_SCOPE_AGENT);
    }
    // ---- phase B: wait for rh tagged s+1; stage own element to LDS ----
    {
      unsigned long long pk;
      for (;;) {
        pk = __hip_atomic_load(&g_rh64[tid], __ATOMIC_RELAXED, __HIP_MEMORY_SCOPE_AGENT);
        if ((unsigned)(pk >> 32) == (unsigned)(s + 1)) break;
      }
      rh_s[tid] = __builtin_bit_cast(float, (unsigned)pk);
    }
    __syncthreads();
    float acc2 = 0.f;
#pragma unroll
    for (int i = 0; i < 16; ++i) acc2 += u1[i] * rh_s[i * 64 + lane];
#pragma unroll
    for (int off = 32; off >= 1; off >>= 1) acc2 += __shfl_xor(acc2, off, 64);
    if (lane == 0) {
      float ht = tanhf(acc2 + ExW[s * 3072 + 2048 + j] + bu);
      float hold = h_s[j];
      float hn = zreg * ht + (1.f - zreg) * hold;
      hs_out[(size_t)s * 1024 + j] = hn;
      __hip_atomic_store(&g_h64[j], packtv((unsigned)(s + 1), hn),
                         __ATOMIC_RELAXED, __HIP_MEMORY_SCOPE_AGENT);
    }
  }
}

// ---------------- bf16 MFMA GEMM: C[M=1024][N] = A(f32,[gather])*B(f32) + bias ----------------
__global__ __launch_bounds__(256, 1) void gemm_mfma(
    const float* __restrict__ A, const int* __restrict__ gidx, int lda,
    const float* __restrict__ B, int ldb,
    const float* __restrict__ bias,
    float* __restrict__ C, int ldc, int N, int K)
{
  __shared__ unsigned short As[128 * GPAD];
  __shared__ unsigned short Bs[128 * GPAD];
  const int tid = threadIdx.x;
  const int lane = tid & 63;
  const int wv = tid >> 6;
  const int wm = wv >> 1, wn = wv & 1;
  const int mbase = blockIdx.y * 128, nbase = blockIdx.x * 128;

  f32x4 acc[4][4];
#pragma unroll
  for (int i = 0; i < 4; ++i)
#pragma unroll
    for (int q = 0; q < 4; ++q) acc[i][q] = (f32x4){0.f, 0.f, 0.f, 0.f};

  const int ar = tid >> 1, ak = (tid & 1) * 16;
  const float* Arow;
  {
    int m = mbase + ar;
    long long gr = gidx ? (long long)gidx[m] : (long long)m;
    Arow = A + (size_t)gr * (size_t)lda;
  }
  const int bn = (tid >> 3) * 4;   // 0..124
  const int bk = (tid & 7) * 4;    // 0..28
  const bool nedge = (nbase + 128 > N);

  const int ksteps = (K + 31) >> 5;
  for (int ks = 0; ks < ksteps; ++ks) {
    const int k0 = ks << 5;
    __syncthreads();
    // stage A: 128 rows x 32 k
    {
      float v[16];
      const int kg = k0 + ak;
      if (kg + 16 <= K) {
#pragma unroll
        for (int q = 0; q < 4; ++q) {
          f32x4 t = *(const f32x4*)(Arow + kg + q * 4);
          v[q * 4 + 0] = t.x; v[q * 4 + 1] = t.y; v[q * 4 + 2] = t.z; v[q * 4 + 3] = t.w;
        }
      } else {
#pragma unroll
        for (int i = 0; i < 16; ++i) v[i] = (kg + i < K) ? Arow[kg + i] : 0.f;
      }
#pragma unroll
      for (int q = 0; q < 4; ++q) {
        u16x4 w;
        w.x = f2bf(v[q * 4 + 0]); w.y = f2bf(v[q * 4 + 1]);
        w.z = f2bf(v[q * 4 + 2]); w.w = f2bf(v[q * 4 + 3]);
        *(u16x4*)&As[ar * GPAD + ak + q * 4] = w;
      }
    }
    // stage B: 32 k x 128 n, transposed into Bs[n][k]
    {
      float bv[4][4];
#pragma unroll
      for (int kk = 0; kk < 4; ++kk) {
        int kglob = k0 + bk + kk;
        if (kglob < K) {
          if (!nedge) {
            f32x4 t = *(const f32x4*)(B + (size_t)kglob * (size_t)ldb + nbase + bn);
            bv[kk][0] = t.x; bv[kk][1] = t.y; bv[kk][2] = t.z; bv[kk][3] = t.w;
          } else {
#pragma unroll
            for (int nn = 0; nn < 4; ++nn) {
              int n = nbase + bn + nn;
              bv[kk][nn] = (n < N) ? B[(size_t)kglob * (size_t)ldb + n] : 0.f;
            }
          }
        } else {
          bv[kk][0] = bv[kk][1] = bv[kk][2] = bv[kk][3] = 0.f;
        }
      }
#pragma unroll
      for (int nn = 0; nn < 4; ++nn) {
        u16x4 w;
        w.x = f2bf(bv[0][nn]); w.y = f2bf(bv[1][nn]);
        w.z = f2bf(bv[2][nn]); w.w = f2bf(bv[3][nn]);
        *(u16x4*)&Bs[(bn + nn) * GPAD + bk] = w;
      }
    }
    __syncthreads();
    bf16x8 af[4], bfr[4];
    const int fr = lane & 15, fk = (lane >> 4) * 8;
#pragma unroll
    for (int mf = 0; mf < 4; ++mf)
      af[mf] = *(const bf16x8*)&As[(wm * 64 + mf * 16 + fr) * GPAD + fk];
#pragma unroll
    for (int nf = 0; nf < 4; ++nf)
      bfr[nf] = *(const bf16x8*)&Bs[(wn * 64 + nf * 16 + fr) * GPAD + fk];
#pragma unroll
    for (int mf = 0; mf < 4; ++mf)
#pragma unroll
      for (int nf = 0; nf < 4; ++nf)
        acc[mf][nf] = __builtin_amdgcn_mfma_f32_16x16x32_bf16(af[mf], bfr[nf], acc[mf][nf], 0, 0, 0);
  }
  // epilogue: C/D layout col=lane&15, row=(lane>>4)*4+reg
  const int fr = lane & 15, fq = lane >> 4;
#pragma unroll
  for (int nf = 0; nf < 4; ++nf) {
    int col = nbase + wn * 64 + nf * 16 + fr;
    if (col < N) {
      float bb = bias ? bias[col] : 0.f;
#pragma unroll
      for (int mf = 0; mf < 4; ++mf) {
        int row0 = mbase + wm * 64 + mf * 16 + fq * 4;
#pragma unroll
        for (int r = 0; r < 4; ++r)
          C[(size_t)(row0 + r) * (size_t)ldc + col] = acc[mf][nf][r] + bb;
      }
    }
  }
}

// ---------------- row-wise log-softmax, in place on d_out ----------------
__global__ __launch_bounds__(256, 1) void logsoftmax_kernel(float* __restrict__ out) {
  const int row = blockIdx.x;
  float* p; int len;
  if (row < 1024) { p = out + (size_t)row * 50000u; len = 50000; }
  else            { p = out + 51200000ull + (size_t)(row - 1024) * 25000u; len = 25000; }
  const int tid = threadIdx.x;
  __shared__ float mred[4], sred[4];

  float m = -3.4e38f;
  for (int i = tid * 4; i < len; i += 1024) {
    f32x4 v = *(const f32x4*)(p + i);
    m = fmaxf(m, fmaxf(fmaxf(v.x, v.y), fmaxf(v.z, v.w)));
  }
#pragma unroll
  for (int off = 32; off >= 1; off >>= 1) m = fmaxf(m, __shfl_xor(m, off, 64));
  if ((tid & 63) == 0) mred[tid >> 6] = m;
  __syncthreads();
  m = fmaxf(fmaxf(mred[0], mred[1]), fmaxf(mred[2], mred[3]));

  float ssum = 0.f;
  for (int i = tid * 4; i < len; i += 1024) {
    f32x4 v = *(const f32x4*)(p + i);
    ssum += __expf(v.x - m) + __expf(v.y - m) + __expf(v.z - m) + __expf(v.w - m);
  }
#pragma unroll
  for (int off = 32; off >= 1; off >>= 1) ssum += __shfl_xor(ssum, off, 64);
  if ((tid & 63) == 0) sred[tid >> 6] = ssum;
  __syncthreads();
  const float lse = m + logf(sred[0] + sred[1] + sred[2] + sred[3]);

  for (int i = tid * 4; i < len; i += 1024) {
    f32x4 v = *(const f32x4*)(p + i);
    v.x -= lse; v.y -= lse; v.z -= lse; v.w -= lse;
    *(f32x4*)(p + i) = v;
  }
}

// ---------------- launch ----------------
extern "C" void kernel_launch(void* const* d_in, const int* in_sizes, int n_in,
                              void* d_out, int out_size, void* d_ws, size_t ws_size,
                              hipStream_t stream) {
  (void)in_sizes; (void)n_in; (void)out_size; (void)d_ws; (void)ws_size;
  const int*   x_idx = (const int*)  d_in[0];
  const float* X     = (const float*)d_in[1];
  const float* W_z_1 = (const float*)d_in[2];
  const float* U_z_1 = (const float*)d_in[3];
  const float* W_r_1 = (const float*)d_in[4];
  const float* U_r_1 = (const float*)d_in[5];
  const float* W_1   = (const float*)d_in[6];
  const float* b_W_1 = (const float*)d_in[7];
  const float* U_1   = (const float*)d_in[8];
  const float* b_U_1 = (const float*)d_in[9];
  const float* W_z_2 = (const float*)d_in[10];
  const float* U_z_2 = (const float*)d_in[11];
  const float* W_r_2 = (const float*)d_in[12];
  const float* U_r_2 = (const float*)d_in[13];
  const float* W_2   = (const float*)d_in[14];
  const float* b_W_2 = (const float*)d_in[15];
  const float* U_2   = (const float*)d_in[16];
  const float* b_U_2 = (const float*)d_in[17];
  const float* W_g   = (const float*)d_in[18];
  const float* b_g   = (const float*)d_in[19];
  const float* W_s   = (const float*)d_in[20];
  const float* b_s   = (const float*)d_in[21];
  float* out = (float*)d_out;

  float *ExW, *hs1, *hs2;
  hipGetSymbolAddress((void**)&ExW, HIP_SYMBOL(g_ExW));
  hipGetSymbolAddress((void**)&hs1, HIP_SYMBOL(g_hs1));
  hipGetSymbolAddress((void**)&hs2, HIP_SYMBOL(g_hs2));

  const dim3 blk(256);

  // layer-1 input projections: E(=X[idx]) @ {W_z_1, W_r_1, W_1}  -> g_ExW
  init_kernel<<<dim3(1), dim3(1024), 0, stream>>>();
  gemm_mfma<<<dim3(8, 8), blk, 0, stream>>>(X, x_idx, 300, W_z_1, 1024, nullptr, ExW + 0,    3072, 1024, 300);
  gemm_mfma<<<dim3(8, 8), blk, 0, stream>>>(X, x_idx, 300, W_r_1, 1024, nullptr, ExW + 1024, 3072, 1024, 300);
  gemm_mfma<<<dim3(8, 8), blk, 0, stream>>>(X, x_idx, 300, W_1,   1024, b_W_1,   ExW + 2048, 3072, 1024, 300);
  // layer-1 scan
  scan_layer<<<dim3(SCAN_WGS), dim3(1024), 0, stream>>>(ExW, U_z_1, U_r_1, U_1, b_U_1, hs1);
  // layer-2 input projections: h1 @ {W_z_2, W_r_2, W_2} -> g_ExW (reuse)
  init_kernel<<<dim3(1), dim3(1024), 0, stream>>>();
  gemm_mfma<<<dim3(8, 8), blk, 0, stream>>>(hs1, nullptr, 1024, W_z_2, 1024, nullptr, ExW + 0,    3072, 1024, 1024);
  gemm_mfma<<<dim3(8, 8), blk, 0, stream>>>(hs1, nullptr, 1024, W_r_2, 1024, nullptr, ExW + 1024, 3072, 1024, 1024);
  gemm_mfma<<<dim3(8, 8), blk, 0, stream>>>(hs1, nullptr, 1024, W_2,   1024, b_W_2,   ExW + 2048, 3072, 1024, 1024);
  // layer-2 scan
  scan_layer<<<dim3(SCAN_WGS), dim3(1024), 0, stream>>>(ExW, U_z_2, U_r_2, U_2, b_U_2, hs2);
  // heads: logits straight into d_out
  gemm_mfma<<<dim3(391, 8), blk, 0, stream>>>(hs2, nullptr, 1024, W_g, 50000, b_g, out,              50000, 50000, 1024);
  gemm_mfma<<<dim3(196, 8), blk, 0, stream>>>(hs2, nullptr, 1024, W_s, 25000, b_s, out + 51200000ll, 25000, 25000, 1024);
  // in-place log-softmax
  logsoftmax_kernel<<<dim3(2048), blk, 0, stream>>>(out);
}

// Round 3
// 10679.235 us; speedup vs baseline: 3.4280x; 1.5549x over previous
//
#include <hip/hip_runtime.h>

typedef __attribute__((ext_vector_type(4))) float f32x4;
typedef __attribute__((ext_vector_type(8))) __bf16 bf16x8;
typedef __attribute__((ext_vector_type(4))) unsigned short u16x4;

#define GPAD 40   // LDS row pad (ushorts): 80B stride -> 16B aligned, 2-way max bank conflict

// ---------------- persistent scratch (module-scope device memory) ----------------
// All cross-WG values are tagged 64-bit words: (step_tag << 32) | f32 bits, moved with
// agent-scope relaxed atomics (bypass non-coherent per-XCD L2s; coherent at L3; the tag
// travels with the value so no fences are needed).
__device__ unsigned long long g_h1cur[1024];   // layer-1 intra-cohort h (single slot, exact tag)
__device__ unsigned long long g_rh1[1024];
__device__ unsigned long long g_h2cur[1024];   // layer-2 intra-cohort h
__device__ unsigned long long g_rh2[1024];
__device__ unsigned long long g_h1s[1024 * 1024];  // cross-layer h1 history: slot s -> tag s+1 (write-once)
__device__ float    g_ExW[1024 * 3072];   // [step][z|r|w] layer-1 input terms
__device__ float    g_hs2[1024 * 1024];

__device__ __forceinline__ unsigned short f2bf(float x) {
  unsigned u = __builtin_bit_cast(unsigned, x);
  u += 0x7FFFu + ((u >> 16) & 1u);   // RNE
  return (unsigned short)(u >> 16);
}

__device__ __forceinline__ unsigned long long packtv(unsigned tag, float v) {
  return ((unsigned long long)tag << 32) | (unsigned long long)__builtin_bit_cast(unsigned, v);
}

__device__ __forceinline__ unsigned long long aload(const unsigned long long* p) {
  return __hip_atomic_load(p, __ATOMIC_RELAXED, __HIP_MEMORY_SCOPE_AGENT);
}
__device__ __forceinline__ void astore(unsigned long long* p, unsigned long long v) {
  __hip_atomic_store(p, v, __ATOMIC_RELAXED, __HIP_MEMORY_SCOPE_AGENT);
}

// ---------------- init: zero state, tag = 0 ----------------
__global__ void init_kernel() {
  int t = threadIdx.x;
  astore(&g_h1cur[t], 0ull);
  astore(&g_rh1[t], 0ull);
  astore(&g_h2cur[t], 0ull);
  astore(&g_rh2[t], 0ull);
}

// ---------------- fused 2-layer persistent GRU scan ----------------
// 128 WGs x 1024 thr. WGs [0,64): layer 1 (consumes precomputed ExW, publishes h1 to the
// write-once slot ring). WGs [64,128): layer 2 (computes its input projections from h1 on
// the fly with W_*2 held in registers, publishes h2 to g_hs2 for the heads).
// Per WG: wave w owns output column j = g*16 + w.
__global__ __launch_bounds__(1024, 1) void fused_scan(
    const float* __restrict__ ExW,
    const float* __restrict__ Uz1, const float* __restrict__ Ur1,
    const float* __restrict__ Uw1, const float* __restrict__ bU1,
    const float* __restrict__ Wz2, const float* __restrict__ Wr2,
    const float* __restrict__ Ww2,
    const float* __restrict__ Uz2, const float* __restrict__ Ur2,
    const float* __restrict__ Uw2,
    const float* __restrict__ bW2, const float* __restrict__ bU2,
    float* __restrict__ hs2)
{
  const int tid = threadIdx.x;
  const int wave = tid >> 6, lane = tid & 63, lm = lane & 31;
  __shared__ float h_s[1024];
  __shared__ float rh_s[1024];
  __shared__ float x_s[2][1024];   // layer-2 h1 staging, double-buffered (no barrier covers it)

  if (blockIdx.x < 64) {
    // ================= layer 1 =================
    const int g = blockIdx.x;
    const int j = g * 16 + wave;
    const float* Um = (lane < 32) ? Uz1 : Ur1;
    float u[32], u1[16];
#pragma unroll
    for (int i = 0; i < 32; ++i) u[i] = Um[(size_t)(i * 32 + lm) * 1024 + j];
#pragma unroll
    for (int i = 0; i < 16; ++i) u1[i] = Uw1[(size_t)(i * 64 + lane) * 1024 + j];
    const float bu = bU1[j];

    float zreg = 0.f;
    for (int s = 0; s < 1024; ++s) {
      // prefetch input terms (complete under the spin below)
      const float xz = ExW[s * 3072 + j];
      const float xr = ExW[s * 3072 + 1024 + j];
      const float xw = ExW[s * 3072 + 2048 + j];
      {
        unsigned long long pk;
        for (;;) { pk = aload(&g_h1cur[tid]); if ((unsigned)(pk >> 32) == (unsigned)s) break; }
        h_s[tid] = __builtin_bit_cast(float, (unsigned)pk);
      }
      __syncthreads();
      float acc = 0.f;
#pragma unroll
      for (int i = 0; i < 32; ++i) acc += u[i] * h_s[i * 32 + lm];
#pragma unroll
      for (int off = 16; off >= 1; off >>= 1) acc += __shfl_xor(acc, off, 64);
      if (lane == 0) {
        zreg = 1.f / (1.f + __expf(-(acc + xz)));
      } else if (lane == 32) {
        float r = 1.f / (1.f + __expf(-(acc + xr)));
        astore(&g_rh1[j], packtv((unsigned)(s + 1), r * h_s[j]));
      }
      {
        unsigned long long pk;
        for (;;) { pk = aload(&g_rh1[tid]); if ((unsigned)(pk >> 32) == (unsigned)(s + 1)) break; }
        rh_s[tid] = __builtin_bit_cast(float, (unsigned)pk);
      }
      __syncthreads();
      float acc2 = 0.f;
#pragma unroll
      for (int i = 0; i < 16; ++i) acc2 += u1[i] * rh_s[i * 64 + lane];
#pragma unroll
      for (int off = 32; off >= 1; off >>= 1) acc2 += __shfl_xor(acc2, off, 64);
      if (lane == 0) {
        float ht = tanhf(acc2 + xw + bu);
        float hn = zreg * ht + (1.f - zreg) * h_s[j];
        unsigned long long o = packtv((unsigned)(s + 1), hn);
        astore(&g_h1cur[j], o);            // intra-cohort first (critical path)
        astore(&g_h1s[(size_t)s * 1024 + j], o);  // cross-layer write-once slot
      }
    }
  } else {
    // ================= layer 2 (input projections fused) =================
    const int g = blockIdx.x - 64;
    const int j = g * 16 + wave;
    const float* Um = (lane < 32) ? Uz2 : Ur2;
    const float* Wm = (lane < 32) ? Wz2 : Wr2;
    float u[32], w[32], u1[16], w1[16];
#pragma unroll
    for (int i = 0; i < 32; ++i) u[i] = Um[(size_t)(i * 32 + lm) * 1024 + j];
#pragma unroll
    for (int i = 0; i < 32; ++i) w[i] = Wm[(size_t)(i * 32 + lm) * 1024 + j];
#pragma unroll
    for (int i = 0; i < 16; ++i) u1[i] = Uw2[(size_t)(i * 64 + lane) * 1024 + j];
#pragma unroll
    for (int i = 0; i < 16; ++i) w1[i] = Ww2[(size_t)(i * 64 + lane) * 1024 + j];
    const float bu = bW2[j] + bU2[j];

    float zreg = 0.f;
    for (int s = 0; s < 1024; ++s) {
      float* xs = x_s[s & 1];
      {
        const unsigned long long* slot = g_h1s + (size_t)s * 1024;
        unsigned long long a = 0, b = 0;
        bool ga = false, gb = false;
        for (;;) {
          if (!ga) { a = aload(&g_h2cur[tid]); ga = ((unsigned)(a >> 32) == (unsigned)s); }
          if (!gb) { b = aload(&slot[tid]);    gb = ((unsigned)(b >> 32) == (unsigned)(s + 1)); }
          if (ga && gb) break;
        }
        h_s[tid] = __builtin_bit_cast(float, (unsigned)a);
        xs[tid]  = __builtin_bit_cast(float, (unsigned)b);
      }
      __syncthreads();
      float acc = 0.f;
#pragma unroll
      for (int i = 0; i < 32; ++i) acc += u[i] * h_s[i * 32 + lm] + w[i] * xs[i * 32 + lm];
#pragma unroll
      for (int off = 16; off >= 1; off >>= 1) acc += __shfl_xor(acc, off, 64);
      if (lane == 0) {
        zreg = 1.f / (1.f + __expf(-acc));
      } else if (lane == 32) {
        float r = 1.f / (1.f + __expf(-acc));
        astore(&g_rh2[j], packtv((unsigned)(s + 1), r * h_s[j]));
      }
      {
        unsigned long long pk;
        for (;;) { pk = aload(&g_rh2[tid]); if ((unsigned)(pk >> 32) == (unsigned)(s + 1)) break; }
        rh_s[tid] = __builtin_bit_cast(float, (unsigned)pk);
      }
      __syncthreads();
      float acc2 = 0.f;
#pragma unroll
      for (int i = 0; i < 16; ++i) acc2 += u1[i] * rh_s[i * 64 + lane] + w1[i] * xs[i * 64 + lane];
#pragma unroll
      for (int off = 32; off >= 1; off >>= 1) acc2 += __shfl_xor(acc2, off, 64);
      if (lane == 0) {
        float ht = tanhf(acc2 + bu);
        float hn = zreg * ht + (1.f - zreg) * h_s[j];
        astore(&g_h2cur[j], packtv((unsigned)(s + 1), hn));
        hs2[(size_t)s * 1024 + j] = hn;
      }
    }
  }
}

// ---------------- bf16 MFMA GEMM: C[M=1024][N] = A(f32,[gather])*B(f32) + bias ----------------
__global__ __launch_bounds__(256, 1) void gemm_mfma(
    const float* __restrict__ A, const int* __restrict__ gidx, int lda,
    const float* __restrict__ B, int ldb,
    const float* __restrict__ bias,
    float* __restrict__ C, int ldc, int N, int K)
{
  __shared__ unsigned short As[128 * GPAD];
  __shared__ unsigned short Bs[128 * GPAD];
  const int tid = threadIdx.x;
  const int lane = tid & 63;
  const int wv = tid >> 6;
  const int wm = wv >> 1, wn = wv & 1;
  const int mbase = blockIdx.y * 128, nbase = blockIdx.x * 128;

  f32x4 acc[4][4];
#pragma unroll
  for (int i = 0; i < 4; ++i)
#pragma unroll
    for (int q = 0; q < 4; ++q) acc[i][q] = (f32x4){0.f, 0.f, 0.f, 0.f};

  const int ar = tid >> 1, ak = (tid & 1) * 16;
  const float* Arow;
  {
    int m = mbase + ar;
    long long gr = gidx ? (long long)gidx[m] : (long long)m;
    Arow = A + (size_t)gr * (size_t)lda;
  }
  const int bn = (tid >> 3) * 4;   // 0..124
  const int bk = (tid & 7) * 4;    // 0..28
  const bool nedge = (nbase + 128 > N);

  const int ksteps = (K + 31) >> 5;
  for (int ks = 0; ks < ksteps; ++ks) {
    const int k0 = ks << 5;
    __syncthreads();
    // stage A: 128 rows x 32 k
    {
      float v[16];
      const int kg = k0 + ak;
      if (kg + 16 <= K) {
#pragma unroll
        for (int q = 0; q < 4; ++q) {
          f32x4 t = *(const f32x4*)(Arow + kg + q * 4);
          v[q * 4 + 0] = t.x; v[q * 4 + 1] = t.y; v[q * 4 + 2] = t.z; v[q * 4 + 3] = t.w;
        }
      } else {
#pragma unroll
        for (int i = 0; i < 16; ++i) v[i] = (kg + i < K) ? Arow[kg + i] : 0.f;
      }
#pragma unroll
      for (int q = 0; q < 4; ++q) {
        u16x4 wq;
        wq.x = f2bf(v[q * 4 + 0]); wq.y = f2bf(v[q * 4 + 1]);
        wq.z = f2bf(v[q * 4 + 2]); wq.w = f2bf(v[q * 4 + 3]);
        *(u16x4*)&As[ar * GPAD + ak + q * 4] = wq;
      }
    }
    // stage B: 32 k x 128 n, transposed into Bs[n][k]
    {
      float bv[4][4];
#pragma unroll
      for (int kk = 0; kk < 4; ++kk) {
        int kglob = k0 + bk + kk;
        if (kglob < K) {
          if (!nedge) {
            f32x4 t = *(const f32x4*)(B + (size_t)kglob * (size_t)ldb + nbase + bn);
            bv[kk][0] = t.x; bv[kk][1] = t.y; bv[kk][2] = t.z; bv[kk][3] = t.w;
          } else {
#pragma unroll
            for (int nn = 0; nn < 4; ++nn) {
              int n = nbase + bn + nn;
              bv[kk][nn] = (n < N) ? B[(size_t)kglob * (size_t)ldb + n] : 0.f;
            }
          }
        } else {
          bv[kk][0] = bv[kk][1] = bv[kk][2] = bv[kk][3] = 0.f;
        }
      }
#pragma unroll
      for (int nn = 0; nn < 4; ++nn) {
        u16x4 wq;
        wq.x = f2bf(bv[0][nn]); wq.y = f2bf(bv[1][nn]);
        wq.z = f2bf(bv[2][nn]); wq.w = f2bf(bv[3][nn]);
        *(u16x4*)&Bs[(bn + nn) * GPAD + bk] = wq;
      }
    }
    __syncthreads();
    bf16x8 af[4], bfr[4];
    const int fr = lane & 15, fk = (lane >> 4) * 8;
#pragma unroll
    for (int mf = 0; mf < 4; ++mf)
      af[mf] = *(const bf16x8*)&As[(wm * 64 + mf * 16 + fr) * GPAD + fk];
#pragma unroll
    for (int nf = 0; nf < 4; ++nf)
      bfr[nf] = *(const bf16x8*)&Bs[(wn * 64 + nf * 16 + fr) * GPAD + fk];
#pragma unroll
    for (int mf = 0; mf < 4; ++mf)
#pragma unroll
      for (int nf = 0; nf < 4; ++nf)
        acc[mf][nf] = __builtin_amdgcn_mfma_f32_16x16x32_bf16(af[mf], bfr[nf], acc[mf][nf], 0, 0, 0);
  }
  // epilogue: C/D layout col=lane&15, row=(lane>>4)*4+reg
  const int fr = lane & 15, fq = lane >> 4;
#pragma unroll
  for (int nf = 0; nf < 4; ++nf) {
    int col = nbase + wn * 64 + nf * 16 + fr;
    if (col < N) {
      float bb = bias ? bias[col] : 0.f;
#pragma unroll
      for (int mf = 0; mf < 4; ++mf) {
        int row0 = mbase + wm * 64 + mf * 16 + fq * 4;
#pragma unroll
        for (int r = 0; r < 4; ++r)
          C[(size_t)(row0 + r) * (size_t)ldc + col] = acc[mf][nf][r] + bb;
      }
    }
  }
}

// ---------------- row-wise log-softmax, in place on d_out ----------------
__global__ __launch_bounds__(256, 1) void logsoftmax_kernel(float* __restrict__ out) {
  const int row = blockIdx.x;
  float* p; int len;
  if (row < 1024) { p = out + (size_t)row * 50000u; len = 50000; }
  else            { p = out + 51200000ull + (size_t)(row - 1024) * 25000u; len = 25000; }
  const int tid = threadIdx.x;
  __shared__ float mred[4], sred[4];

  float m = -3.4e38f;
  for (int i = tid * 4; i < len; i += 1024) {
    f32x4 v = *(const f32x4*)(p + i);
    m = fmaxf(m, fmaxf(fmaxf(v.x, v.y), fmaxf(v.z, v.w)));
  }
#pragma unroll
  for (int off = 32; off >= 1; off >>= 1) m = fmaxf(m, __shfl_xor(m, off, 64));
  if ((tid & 63) == 0) mred[tid >> 6] = m;
  __syncthreads();
  m = fmaxf(fmaxf(mred[0], mred[1]), fmaxf(mred[2], mred[3]));

  float ssum = 0.f;
  for (int i = tid * 4; i < len; i += 1024) {
    f32x4 v = *(const f32x4*)(p + i);
    ssum += __expf(v.x - m) + __expf(v.y - m) + __expf(v.z - m) + __expf(v.w - m);
  }
#pragma unroll
  for (int off = 32; off >= 1; off >>= 1) ssum += __shfl_xor(ssum, off, 64);
  if ((tid & 63) == 0) sred[tid >> 6] = ssum;
  __syncthreads();
  const float lse = m + logf(sred[0] + sred[1] + sred[2] + sred[3]);

  for (int i = tid * 4; i < len; i += 1024) {
    f32x4 v = *(const f32x4*)(p + i);
    v.x -= lse; v.y -= lse; v.z -= lse; v.w -= lse;
    *(f32x4*)(p + i) = v;
  }
}

// ---------------- launch ----------------
extern "C" void kernel_launch(void* const* d_in, const int* in_sizes, int n_in,
                              void* d_out, int out_size, void* d_ws, size_t ws_size,
                              hipStream_t stream) {
  (void)in_sizes; (void)n_in; (void)out_size; (void)d_ws; (void)ws_size;
  const int*   x_idx = (const int*)  d_in[0];
  const float* X     = (const float*)d_in[1];
  const float* W_z_1 = (const float*)d_in[2];
  const float* U_z_1 = (const float*)d_in[3];
  const float* W_r_1 = (const float*)d_in[4];
  const float* U_r_1 = (const float*)d_in[5];
  const float* W_1   = (const float*)d_in[6];
  const float* b_W_1 = (const float*)d_in[7];
  const float* U_1   = (const float*)d_in[8];
  const float* b_U_1 = (const float*)d_in[9];
  const float* W_z_2 = (const float*)d_in[10];
  const float* U_z_2 = (const float*)d_in[11];
  const float* W_r_2 = (const float*)d_in[12];
  const float* U_r_2 = (const float*)d_in[13];
  const float* W_2   = (const float*)d_in[14];
  const float* b_W_2 = (const float*)d_in[15];
  const float* U_2   = (const float*)d_in[16];
  const float* b_U_2 = (const float*)d_in[17];
  const float* W_g   = (const float*)d_in[18];
  const float* b_g   = (const float*)d_in[19];
  const float* W_s   = (const float*)d_in[20];
  const float* b_s   = (const float*)d_in[21];
  float* out = (float*)d_out;

  float *ExW, *hs2;
  unsigned long long* h1s;
  hipGetSymbolAddress((void**)&ExW, HIP_SYMBOL(g_ExW));
  hipGetSymbolAddress((void**)&hs2, HIP_SYMBOL(g_hs2));
  hipGetSymbolAddress((void**)&h1s, HIP_SYMBOL(g_h1s));

  const dim3 blk(256);

  // reset sync state (every launch: graph replays must be self-contained)
  init_kernel<<<dim3(1), dim3(1024), 0, stream>>>();
  hipMemsetAsync(h1s, 0, 1024 * 1024 * sizeof(unsigned long long), stream);

  // layer-1 input projections: E(=X[idx]) @ {W_z_1, W_r_1, W_1}  -> g_ExW
  gemm_mfma<<<dim3(8, 8), blk, 0, stream>>>(X, x_idx, 300, W_z_1, 1024, nullptr, ExW + 0,    3072, 1024, 300);
  gemm_mfma<<<dim3(8, 8), blk, 0, stream>>>(X, x_idx, 300, W_r_1, 1024, nullptr, ExW + 1024, 3072, 1024, 300);
  gemm_mfma<<<dim3(8, 8), blk, 0, stream>>>(X, x_idx, 300, W_1,   1024, b_W_1,   ExW + 2048, 3072, 1024, 300);

  // fused two-layer pipelined scan
  fused_scan<<<dim3(128), dim3(1024), 0, stream>>>(
      ExW, U_z_1, U_r_1, U_1, b_U_1,
      W_z_2, W_r_2, W_2, U_z_2, U_r_2, U_2, b_W_2, b_U_2, hs2);

  // heads: logits straight into d_out
  gemm_mfma<<<dim3(391, 8), blk, 0, stream>>>(hs2, nullptr, 1024, W_g, 50000, b_g, out,              50000, 50000, 1024);
  gemm_mfma<<<dim3(196, 8), blk, 0, stream>>>(hs2, nullptr, 1024, W_s, 25000, b_s, out + 51200000ll, 25000, 25000, 1024);
  // in-place log-softmax
  logsoftmax_kernel<<<dim3(2048), blk, 0, stream>>>(out);
}

// Round 4
// 10445.097 us; speedup vs baseline: 3.5049x; 1.0224x over previous
//
#include <hip/hip_runtime.h>

typedef __attribute__((ext_vector_type(4))) float f32x4;
typedef __attribute__((ext_vector_type(8))) __bf16 bf16x8;
typedef __attribute__((ext_vector_type(4))) unsigned short u16x4;

#define GPAD 40   // LDS row pad (ushorts): 80B stride -> 16B aligned, 2-way max bank conflict

// Force a value to be materialized (and kept) in a VGPR at this point.
#define KEEPF(x) asm volatile("" : "+v"(x))

// ---------------- persistent scratch (module-scope device memory) ----------------
// All cross-WG values are tagged 64-bit words: (step_tag << 32) | f32 bits, moved with
// agent-scope relaxed atomics (bypass non-coherent per-XCD L2s; coherent at L3; the tag
// travels with the value so no fences are needed).
// g_h1s is a write-once ring: slot t holds h1 after t steps, tagged t (slot 0 = zeros via
// memset, pre-valid). Layer-1 polls slot s, publishes slot s+1. Layer-2 polls slot s+1.
__device__ unsigned long long g_h1s[1025 * 1024];
__device__ unsigned long long g_rh1[1024];
__device__ unsigned long long g_h2cur[1024];
__device__ unsigned long long g_rh2[1024];
__device__ float    g_ExW[1024 * 3072];   // [step][z|r|w] layer-1 input terms
__device__ float    g_hs2[1024 * 1024];

__device__ __forceinline__ unsigned short f2bf(float x) {
  unsigned u = __builtin_bit_cast(unsigned, x);
  u += 0x7FFFu + ((u >> 16) & 1u);   // RNE
  return (unsigned short)(u >> 16);
}

__device__ __forceinline__ unsigned long long packtv(unsigned tag, float v) {
  return ((unsigned long long)tag << 32) | (unsigned long long)__builtin_bit_cast(unsigned, v);
}

__device__ __forceinline__ unsigned long long aload(const unsigned long long* p) {
  return __hip_atomic_load(p, __ATOMIC_RELAXED, __HIP_MEMORY_SCOPE_AGENT);
}
__device__ __forceinline__ void astore(unsigned long long* p, unsigned long long v) {
  __hip_atomic_store(p, v, __ATOMIC_RELAXED, __HIP_MEMORY_SCOPE_AGENT);
}

// ---------------- init: zero single-slot state, tag = 0 ----------------
__global__ void init_kernel() {
  int t = threadIdx.x;
  astore(&g_rh1[t], 0ull);
  astore(&g_h2cur[t], 0ull);
  astore(&g_rh2[t], 0ull);
}

// ---------------- fused 2-layer persistent GRU scan ----------------
// 128 WGs x 1024 thr. WGs [0,64): layer 1. WGs [64,128): layer 2 (input projections
// computed on the fly; W-dots are computed EARLY, before the h2/rh2 polls, so their
// weight-load latency hides under the poll wait). U-weights are VGPR-pinned.
__global__ __launch_bounds__(1024, 1) void fused_scan(
    const float* __restrict__ ExW,
    const float* __restrict__ Uz1, const float* __restrict__ Ur1,
    const float* __restrict__ Uw1, const float* __restrict__ bU1,
    const float* __restrict__ Wz2, const float* __restrict__ Wr2,
    const float* __restrict__ Ww2,
    const float* __restrict__ Uz2, const float* __restrict__ Ur2,
    const float* __restrict__ Uw2,
    const float* __restrict__ bW2, const float* __restrict__ bU2,
    float* __restrict__ hs2)
{
  const int tid = threadIdx.x;
  const int wave = tid >> 6, lane = tid & 63, lm = lane & 31;
  __shared__ float h_s[1024];
  __shared__ float rh_s[1024];
  __shared__ float x_s[2][1024];   // layer-2 h1 staging, double-buffered

  if (blockIdx.x < 64) {
    // ================= layer 1 =================
    const int g = blockIdx.x;
    const int j = g * 16 + wave;
    const float* Um = (lane < 32) ? Uz1 : Ur1;
    float u[32], u1[16];
#pragma unroll
    for (int i = 0; i < 32; ++i) u[i] = Um[(size_t)(i * 32 + lm) * 1024 + j];
#pragma unroll
    for (int i = 0; i < 16; ++i) u1[i] = Uw1[(size_t)(i * 64 + lane) * 1024 + j];
#pragma unroll
    for (int i = 0; i < 32; ++i) KEEPF(u[i]);
#pragma unroll
    for (int i = 0; i < 16; ++i) KEEPF(u1[i]);
    const float bu = bU1[j];

    float zreg = 0.f;
    for (int s = 0; s < 1024; ++s) {
      // prefetch input terms; pin so they are resident before the poll
      float xz = ExW[s * 3072 + j];
      float xr = ExW[s * 3072 + 1024 + j];
      float xw = ExW[s * 3072 + 2048 + j];
      KEEPF(xz); KEEPF(xr); KEEPF(xw);
      {
        const unsigned long long* sl = g_h1s + (size_t)s * 1024;
        unsigned long long pk = aload(&sl[tid]);
        while ((unsigned)(pk >> 32) != (unsigned)s) {
          __builtin_amdgcn_s_sleep(1);
          pk = aload(&sl[tid]);
        }
        h_s[tid] = __builtin_bit_cast(float, (unsigned)pk);
      }
      __syncthreads();
      float acc = 0.f;
#pragma unroll
      for (int i = 0; i < 32; ++i) acc += u[i] * h_s[i * 32 + lm];
#pragma unroll
      for (int off = 16; off >= 1; off >>= 1) acc += __shfl_xor(acc, off, 64);
      if (lane == 0) {
        zreg = 1.f / (1.f + __expf(-(acc + xz)));
      } else if (lane == 32) {
        float r = 1.f / (1.f + __expf(-(acc + xr)));
        astore(&g_rh1[j], packtv((unsigned)(s + 1), r * h_s[j]));
      }
      {
        unsigned long long pk = aload(&g_rh1[tid]);
        while ((unsigned)(pk >> 32) != (unsigned)(s + 1)) {
          __builtin_amdgcn_s_sleep(1);
          pk = aload(&g_rh1[tid]);
        }
        rh_s[tid] = __builtin_bit_cast(float, (unsigned)pk);
      }
      __syncthreads();
      float acc2 = 0.f;
#pragma unroll
      for (int i = 0; i < 16; ++i) acc2 += u1[i] * rh_s[i * 64 + lane];
#pragma unroll
      for (int off = 32; off >= 1; off >>= 1) acc2 += __shfl_xor(acc2, off, 64);
      if (lane == 0) {
        float ht = tanhf(acc2 + xw + bu);
        float hn = zreg * ht + (1.f - zreg) * h_s[j];
        astore(&g_h1s[(size_t)(s + 1) * 1024 + j], packtv((unsigned)(s + 1), hn));
      }
    }
  } else {
    // ================= layer 2 =================
    const int g = blockIdx.x - 64;
    const int j = g * 16 + wave;
    const float* Um = (lane < 32) ? Uz2 : Ur2;
    const float* Wm = (lane < 32) ? Wz2 : Wr2;
    float u[32], u1[16];
#pragma unroll
    for (int i = 0; i < 32; ++i) u[i] = Um[(size_t)(i * 32 + lm) * 1024 + j];
#pragma unroll
    for (int i = 0; i < 16; ++i) u1[i] = Uw2[(size_t)(i * 64 + lane) * 1024 + j];
#pragma unroll
    for (int i = 0; i < 32; ++i) KEEPF(u[i]);
#pragma unroll
    for (int i = 0; i < 16; ++i) KEEPF(u1[i]);
    // W-weights intentionally NOT pinned: reloaded in-loop (L2-resident), used in the
    // early W-dots whose latency hides under the h2/rh2 poll waits.
    const float bu = bW2[j] + bU2[j];

    float zreg = 0.f;
    for (int s = 0; s < 1024; ++s) {
      float* xs = x_s[s & 1];
      // ---- slot poll (layer 1 runs ahead; usually ready) ----
      {
        const unsigned long long* sl = g_h1s + (size_t)(s + 1) * 1024;
        unsigned long long pk = aload(&sl[tid]);
        while ((unsigned)(pk >> 32) != (unsigned)(s + 1)) {
          __builtin_amdgcn_s_sleep(1);
          pk = aload(&sl[tid]);
        }
        xs[tid] = __builtin_bit_cast(float, (unsigned)pk);
      }
      __syncthreads();
      // ---- early W-dot (z|r) on x; off the critical path ----
      float wacc = 0.f;
#pragma unroll
      for (int i = 0; i < 32; ++i) wacc += Wm[(size_t)(i * 32 + lm) * 1024 + j] * xs[i * 32 + lm];
      // ---- h2 poll ----
      {
        unsigned long long pk = aload(&g_h2cur[tid]);
        while ((unsigned)(pk >> 32) != (unsigned)s) {
          __builtin_amdgcn_s_sleep(1);
          pk = aload(&g_h2cur[tid]);
        }
        h_s[tid] = __builtin_bit_cast(float, (unsigned)pk);
      }
      __syncthreads();
      float acc = wacc;
#pragma unroll
      for (int i = 0; i < 32; ++i) acc += u[i] * h_s[i * 32 + lm];
#pragma unroll
      for (int off = 16; off >= 1; off >>= 1) acc += __shfl_xor(acc, off, 64);
      if (lane == 0) {
        zreg = 1.f / (1.f + __expf(-acc));
      } else if (lane == 32) {
        float r = 1.f / (1.f + __expf(-acc));
        astore(&g_rh2[j], packtv((unsigned)(s + 1), r * h_s[j]));
      }
      // ---- early W-dot (w-gate) on x ----
      float w1acc = 0.f;
#pragma unroll
      for (int i = 0; i < 16; ++i) w1acc += Ww2[(size_t)(i * 64 + lane) * 1024 + j] * xs[i * 64 + lane];
      // ---- rh2 poll ----
      {
        unsigned long long pk = aload(&g_rh2[tid]);
        while ((unsigned)(pk >> 32) != (unsigned)(s + 1)) {
          __builtin_amdgcn_s_sleep(1);
          pk = aload(&g_rh2[tid]);
        }
        rh_s[tid] = __builtin_bit_cast(float, (unsigned)pk);
      }
      __syncthreads();
      float acc2 = w1acc;
#pragma unroll
      for (int i = 0; i < 16; ++i) acc2 += u1[i] * rh_s[i * 64 + lane];
#pragma unroll
      for (int off = 32; off >= 1; off >>= 1) acc2 += __shfl_xor(acc2, off, 64);
      if (lane == 0) {
        float ht = tanhf(acc2 + bu);
        float hn = zreg * ht + (1.f - zreg) * h_s[j];
        astore(&g_h2cur[j], packtv((unsigned)(s + 1), hn));
        hs2[(size_t)s * 1024 + j] = hn;
      }
    }
  }
}

// ---------------- bf16 MFMA GEMM: C[M=1024][N] = A(f32,[gather])*B(f32) + bias ----------------
__global__ __launch_bounds__(256, 1) void gemm_mfma(
    const float* __restrict__ A, const int* __restrict__ gidx, int lda,
    const float* __restrict__ B, int ldb,
    const float* __restrict__ bias,
    float* __restrict__ C, int ldc, int N, int K)
{
  __shared__ unsigned short As[128 * GPAD];
  __shared__ unsigned short Bs[128 * GPAD];
  const int tid = threadIdx.x;
  const int lane = tid & 63;
  const int wv = tid >> 6;
  const int wm = wv >> 1, wn = wv & 1;
  const int mbase = blockIdx.y * 128, nbase = blockIdx.x * 128;

  f32x4 acc[4][4];
#pragma unroll
  for (int i = 0; i < 4; ++i)
#pragma unroll
    for (int q = 0; q < 4; ++q) acc[i][q] = (f32x4){0.f, 0.f, 0.f, 0.f};

  const int ar = tid >> 1, ak = (tid & 1) * 16;
  const float* Arow;
  {
    int m = mbase + ar;
    long long gr = gidx ? (long long)gidx[m] : (long long)m;
    Arow = A + (size_t)gr * (size_t)lda;
  }
  const int bn = (tid >> 3) * 4;   // 0..124
  const int bk = (tid & 7) * 4;    // 0..28
  const bool nedge = (nbase + 128 > N);

  const int ksteps = (K + 31) >> 5;
  for (int ks = 0; ks < ksteps; ++ks) {
    const int k0 = ks << 5;
    __syncthreads();
    // stage A: 128 rows x 32 k
    {
      float v[16];
      const int kg = k0 + ak;
      if (kg + 16 <= K) {
#pragma unroll
        for (int q = 0; q < 4; ++q) {
          f32x4 t = *(const f32x4*)(Arow + kg + q * 4);
          v[q * 4 + 0] = t.x; v[q * 4 + 1] = t.y; v[q * 4 + 2] = t.z; v[q * 4 + 3] = t.w;
        }
      } else {
#pragma unroll
        for (int i = 0; i < 16; ++i) v[i] = (kg + i < K) ? Arow[kg + i] : 0.f;
      }
#pragma unroll
      for (int q = 0; q < 4; ++q) {
        u16x4 wq;
        wq.x = f2bf(v[q * 4 + 0]); wq.y = f2bf(v[q * 4 + 1]);
        wq.z = f2bf(v[q * 4 + 2]); wq.w = f2bf(v[q * 4 + 3]);
        *(u16x4*)&As[ar * GPAD + ak + q * 4] = wq;
      }
    }
    // stage B: 32 k x 128 n, transposed into Bs[n][k]
    {
      float bv[4][4];
#pragma unroll
      for (int kk = 0; kk < 4; ++kk) {
        int kglob = k0 + bk + kk;
        if (kglob < K) {
          if (!nedge) {
            f32x4 t = *(const f32x4*)(B + (size_t)kglob * (size_t)ldb + nbase + bn);
            bv[kk][0] = t.x; bv[kk][1] = t.y; bv[kk][2] = t.z; bv[kk][3] = t.w;
          } else {
#pragma unroll
            for (int nn = 0; nn < 4; ++nn) {
              int n = nbase + bn + nn;
              bv[kk][nn] = (n < N) ? B[(size_t)kglob * (size_t)ldb + n] : 0.f;
            }
          }
        } else {
          bv[kk][0] = bv[kk][1] = bv[kk][2] = bv[kk][3] = 0.f;
        }
      }
#pragma unroll
      for (int nn = 0; nn < 4; ++nn) {
        u16x4 wq;
        wq.x = f2bf(bv[0][nn]); wq.y = f2bf(bv[1][nn]);
        wq.z = f2bf(bv[2][nn]); wq.w = f2bf(bv[3][nn]);
        *(u16x4*)&Bs[(bn + nn) * GPAD + bk] = wq;
      }
    }
    __syncthreads();
    bf16x8 af[4], bfr[4];
    const int fr = lane & 15, fk = (lane >> 4) * 8;
#pragma unroll
    for (int mf = 0; mf < 4; ++mf)
      af[mf] = *(const bf16x8*)&As[(wm * 64 + mf * 16 + fr) * GPAD + fk];
#pragma unroll
    for (int nf = 0; nf < 4; ++nf)
      bfr[nf] = *(const bf16x8*)&Bs[(wn * 64 + nf * 16 + fr) * GPAD + fk];
#pragma unroll
    for (int mf = 0; mf < 4; ++mf)
#pragma unroll
      for (int nf = 0; nf < 4; ++nf)
        acc[mf][nf] = __builtin_amdgcn_mfma_f32_16x16x32_bf16(af[mf], bfr[nf], acc[mf][nf], 0, 0, 0);
  }
  // epilogue: C/D layout col=lane&15, row=(lane>>4)*4+reg
  const int fr = lane & 15, fq = lane >> 4;
#pragma unroll
  for (int nf = 0; nf < 4; ++nf) {
    int col = nbase + wn * 64 + nf * 16 + fr;
    if (col < N) {
      float bb = bias ? bias[col] : 0.f;
#pragma unroll
      for (int mf = 0; mf < 4; ++mf) {
        int row0 = mbase + wm * 64 + mf * 16 + fq * 4;
#pragma unroll
        for (int r = 0; r < 4; ++r)
          C[(size_t)(row0 + r) * (size_t)ldc + col] = acc[mf][nf][r] + bb;
      }
    }
  }
}

// ---------------- row-wise log-softmax, in place on d_out ----------------
__global__ __launch_bounds__(256, 1) void logsoftmax_kernel(float* __restrict__ out) {
  const int row = blockIdx.x;
  float* p; int len;
  if (row < 1024) { p = out + (size_t)row * 50000u; len = 50000; }
  else            { p = out + 51200000ull + (size_t)(row - 1024) * 25000u; len = 25000; }
  const int tid = threadIdx.x;
  __shared__ float mred[4], sred[4];

  float m = -3.4e38f;
  for (int i = tid * 4; i < len; i += 1024) {
    f32x4 v = *(const f32x4*)(p + i);
    m = fmaxf(m, fmaxf(fmaxf(v.x, v.y), fmaxf(v.z, v.w)));
  }
#pragma unroll
  for (int off = 32; off >= 1; off >>= 1) m = fmaxf(m, __shfl_xor(m, off, 64));
  if ((tid & 63) == 0) mred[tid >> 6] = m;
  __syncthreads();
  m = fmaxf(fmaxf(mred[0], mred[1]), fmaxf(mred[2], mred[3]));

  float ssum = 0.f;
  for (int i = tid * 4; i < len; i += 1024) {
    f32x4 v = *(const f32x4*)(p + i);
    ssum += __expf(v.x - m) + __expf(v.y - m) + __expf(v.z - m) + __expf(v.w - m);
  }
#pragma unroll
  for (int off = 32; off >= 1; off >>= 1) ssum += __shfl_xor(ssum, off, 64);
  if ((tid & 63) == 0) sred[tid >> 6] = ssum;
  __syncthreads();
  const float lse = m + logf(sred[0] + sred[1] + sred[2] + sred[3]);

  for (int i = tid * 4; i < len; i += 1024) {
    f32x4 v = *(const f32x4*)(p + i);
    v.x -= lse; v.y -= lse; v.z -= lse; v.w -= lse;
    *(f32x4*)(p + i) = v;
  }
}

// ---------------- launch ----------------
extern "C" void kernel_launch(void* const* d_in, const int* in_sizes, int n_in,
                              void* d_out, int out_size, void* d_ws, size_t ws_size,
                              hipStream_t stream) {
  (void)in_sizes; (void)n_in; (void)out_size; (void)d_ws; (void)ws_size;
  const int*   x_idx = (const int*)  d_in[0];
  const float* X     = (const float*)d_in[1];
  const float* W_z_1 = (const float*)d_in[2];
  const float* U_z_1 = (const float*)d_in[3];
  const float* W_r_1 = (const float*)d_in[4];
  const float* U_r_1 = (const float*)d_in[5];
  const float* W_1   = (const float*)d_in[6];
  const float* b_W_1 = (const float*)d_in[7];
  const float* U_1   = (const float*)d_in[8];
  const float* b_U_1 = (const float*)d_in[9];
  const float* W_z_2 = (const float*)d_in[10];
  const float* U_z_2 = (const float*)d_in[11];
  const float* W_r_2 = (const float*)d_in[12];
  const float* U_r_2 = (const float*)d_in[13];
  const float* W_2   = (const float*)d_in[14];
  const float* b_W_2 = (const float*)d_in[15];
  const float* U_2   = (const float*)d_in[16];
  const float* b_U_2 = (const float*)d_in[17];
  const float* W_g   = (const float*)d_in[18];
  const float* b_g   = (const float*)d_in[19];
  const float* W_s   = (const float*)d_in[20];
  const float* b_s   = (const float*)d_in[21];
  float* out = (float*)d_out;

  float *ExW, *hs2;
  unsigned long long* h1s;
  hipGetSymbolAddress((void**)&ExW, HIP_SYMBOL(g_ExW));
  hipGetSymbolAddress((void**)&hs2, HIP_SYMBOL(g_hs2));
  hipGetSymbolAddress((void**)&h1s, HIP_SYMBOL(g_h1s));

  const dim3 blk(256);

  // reset sync state (every launch: graph replays must be self-contained)
  init_kernel<<<dim3(1), dim3(1024), 0, stream>>>();
  hipMemsetAsync(h1s, 0, 1025ull * 1024 * sizeof(unsigned long long), stream);

  // layer-1 input projections: E(=X[idx]) @ {W_z_1, W_r_1, W_1}  -> g_ExW
  gemm_mfma<<<dim3(8, 8), blk, 0, stream>>>(X, x_idx, 300, W_z_1, 1024, nullptr, ExW + 0,    3072, 1024, 300);
  gemm_mfma<<<dim3(8, 8), blk, 0, stream>>>(X, x_idx, 300, W_r_1, 1024, nullptr, ExW + 1024, 3072, 1024, 300);
  gemm_mfma<<<dim3(8, 8), blk, 0, stream>>>(X, x_idx, 300, W_1,   1024, b_W_1,   ExW + 2048, 3072, 1024, 300);

  // fused two-layer pipelined scan
  fused_scan<<<dim3(128), dim3(1024), 0, stream>>>(
      ExW, U_z_1, U_r_1, U_1, b_U_1,
      W_z_2, W_r_2, W_2, U_z_2, U_r_2, U_2, b_W_2, b_U_2, hs2);

  // heads: logits straight into d_out
  gemm_mfma<<<dim3(391, 8), blk, 0, stream>>>(hs2, nullptr, 1024, W_g, 50000, b_g, out,              50000, 50000, 1024);
  gemm_mfma<<<dim3(196, 8), blk, 0, stream>>>(hs2, nullptr, 1024, W_s, 25000, b_s, out + 51200000ll, 25000, 25000, 1024);
  // in-place log-softmax
  logsoftmax_kernel<<<dim3(2048), blk, 0, stream>>>(out);
}

// Round 5
// 8036.533 us; speedup vs baseline: 4.5553x; 1.2997x over previous
//
#include <hip/hip_runtime.h>

typedef __attribute__((ext_vector_type(4))) float f32x4;
typedef __attribute__((ext_vector_type(8))) __bf16 bf16x8;
typedef __attribute__((ext_vector_type(4))) unsigned short u16x4;

#define GPAD 40   // GEMM LDS row pad (ushorts)
#define KEEPF(x) asm volatile("" : "+v"(x))
#define PHYS(i) ((i) + (((i) >> 6) << 2))   // +4 words pad per 64 -> conflict-free b128 slices

// ---------------- persistent scratch ----------------
// Tagged 64-bit words: (step_tag << 32) | f32 bits, agent-scope relaxed atomics (L3-coherent,
// no fences; tag travels with value). g_h1s: write-once ring, slot t = h1 after t steps, tag t.
__device__ unsigned long long g_h1s[1025 * 1024];
__device__ unsigned long long g_rh1[1024];
__device__ unsigned long long g_h2cur[1024];
__device__ unsigned long long g_rh2[1024];
__device__ float g_ExW[1024 * 3072];   // [step][z|r|w] layer-1 input terms
__device__ float g_hs2[1024 * 1024];

__device__ __forceinline__ unsigned short f2bf(float x) {
  unsigned u = __builtin_bit_cast(unsigned, x);
  u += 0x7FFFu + ((u >> 16) & 1u);   // RNE
  return (unsigned short)(u >> 16);
}
__device__ __forceinline__ unsigned long long packtv(unsigned tag, float v) {
  return ((unsigned long long)tag << 32) | (unsigned long long)__builtin_bit_cast(unsigned, v);
}
__device__ __forceinline__ unsigned long long aload(const unsigned long long* p) {
  return __hip_atomic_load(p, __ATOMIC_RELAXED, __HIP_MEMORY_SCOPE_AGENT);
}
__device__ __forceinline__ void astore(unsigned long long* p, unsigned long long v) {
  __hip_atomic_store(p, v, __ATOMIC_RELAXED, __HIP_MEMORY_SCOPE_AGENT);
}
__device__ __forceinline__ float lo32(unsigned long long v) {
  return __builtin_bit_cast(float, (unsigned)v);
}

__global__ void init_kernel() {
  int t = threadIdx.x;
  astore(&g_rh1[t], 0ull);
  astore(&g_h2cur[t], 0ull);
  astore(&g_rh2[t], 0ull);
}

// ---------------- fused 2-layer persistent GRU scan ----------------
// 128 WGs x 256 thr (4 waves). WGs [0,64): layer 1; [64,128): layer 2 (input projections
// fused, all weights register-resident). Thread (c=tid&15,q=tid>>4) owns column j=g*16+c,
// slice [q*64,(q+1)*64). Reduce: shfl_xor(16,32) within wave, then 4x16 LDS partials.
__global__ __launch_bounds__(256, 1) void fused_scan(
    const float* __restrict__ ExW,
    const float* __restrict__ Uz1, const float* __restrict__ Ur1,
    const float* __restrict__ Uw1, const float* __restrict__ bU1,
    const float* __restrict__ Wz2, const float* __restrict__ Wr2,
    const float* __restrict__ Ww2,
    const float* __restrict__ Uz2, const float* __restrict__ Ur2,
    const float* __restrict__ Uw2,
    const float* __restrict__ bW2, const float* __restrict__ bU2,
    float* __restrict__ hs2)
{
  const int tid = threadIdx.x;
  const int c = tid & 15, q = tid >> 4;
  const int inw = tid & 63, wv = tid >> 6;
  __shared__ __align__(16) float h_s[1088];
  __shared__ __align__(16) float rh_s[1088];
  __shared__ __align__(16) float x_s[1088];
  __shared__ float pz[4][16], pr[4][16], pw[4][16];

  if (blockIdx.x < 64) {
    // ================= layer 1 =================
    const int g = blockIdx.x;
    const int j = g * 16 + c;
    float uz[64], ur[64], uw[64];
#pragma unroll
    for (int i = 0; i < 64; ++i) uz[i] = Uz1[(size_t)(q * 64 + i) * 1024 + j];
#pragma unroll
    for (int i = 0; i < 64; ++i) ur[i] = Ur1[(size_t)(q * 64 + i) * 1024 + j];
#pragma unroll
    for (int i = 0; i < 64; ++i) uw[i] = Uw1[(size_t)(q * 64 + i) * 1024 + j];
#pragma unroll
    for (int i = 0; i < 64; ++i) { KEEPF(uz[i]); KEEPF(ur[i]); KEEPF(uw[i]); }
    const float bu = bU1[j];

    float zreg = 0.f, hold = 0.f;
    for (int s = 0; s < 1024; ++s) {
      float xz = 0.f, xr = 0.f, xw = 0.f;
      if (tid < 16) { xz = ExW[s * 3072 + j]; xw = ExW[s * 3072 + 2048 + j]; }
      else if (tid < 32) { xr = ExW[s * 3072 + 1024 + j]; }
      // ---- poll h ring slot s (tag s) ----
      {
        const unsigned long long* sl = g_h1s + (size_t)s * 1024 + tid * 4;
        unsigned long long a0, a1, a2, a3;
        for (;;) {
          a0 = aload(sl); a1 = aload(sl + 1); a2 = aload(sl + 2); a3 = aload(sl + 3);
          unsigned bad = ((unsigned)(a0 >> 32) ^ (unsigned)s) | ((unsigned)(a1 >> 32) ^ (unsigned)s) |
                         ((unsigned)(a2 >> 32) ^ (unsigned)s) | ((unsigned)(a3 >> 32) ^ (unsigned)s);
          if (bad == 0u) break;
          __builtin_amdgcn_s_sleep(1);
        }
        f32x4 v; v.x = lo32(a0); v.y = lo32(a1); v.z = lo32(a2); v.w = lo32(a3);
        *(f32x4*)&h_s[PHYS(tid * 4)] = v;
      }
      __syncthreads();   // A1
      float az = 0.f, ar = 0.f;
      {
        const float* hp = h_s + q * 68;
#pragma unroll
        for (int i2 = 0; i2 < 16; ++i2) {
          f32x4 hv = *(const f32x4*)(hp + i2 * 4);
          az = fmaf(uz[i2 * 4 + 0], hv.x, az); az = fmaf(uz[i2 * 4 + 1], hv.y, az);
          az = fmaf(uz[i2 * 4 + 2], hv.z, az); az = fmaf(uz[i2 * 4 + 3], hv.w, az);
          ar = fmaf(ur[i2 * 4 + 0], hv.x, ar); ar = fmaf(ur[i2 * 4 + 1], hv.y, ar);
          ar = fmaf(ur[i2 * 4 + 2], hv.z, ar); ar = fmaf(ur[i2 * 4 + 3], hv.w, ar);
        }
      }
      az += __shfl_xor(az, 16, 64); az += __shfl_xor(az, 32, 64);
      ar += __shfl_xor(ar, 16, 64); ar += __shfl_xor(ar, 32, 64);
      if (inw < 16) { pz[wv][c] = az; pr[wv][c] = ar; }
      __syncthreads();   // A2
      if (tid < 32) {
        if (tid < 16) {
          float zz = pz[0][c] + pz[1][c] + pz[2][c] + pz[3][c] + xz;
          zreg = 1.f / (1.f + __expf(-zz));
          hold = h_s[PHYS(j)];
        } else {
          float rr = pr[0][c] + pr[1][c] + pr[2][c] + pr[3][c] + xr;
          float r = 1.f / (1.f + __expf(-rr));
          astore(&g_rh1[j], packtv((unsigned)(s + 1), r * h_s[PHYS(j)]));
        }
      }
      // ---- poll rh (tag s+1) ----
      {
        const unsigned long long* sl = g_rh1 + tid * 4;
        unsigned long long a0, a1, a2, a3;
        const unsigned tg = (unsigned)(s + 1);
        for (;;) {
          a0 = aload(sl); a1 = aload(sl + 1); a2 = aload(sl + 2); a3 = aload(sl + 3);
          unsigned bad = ((unsigned)(a0 >> 32) ^ tg) | ((unsigned)(a1 >> 32) ^ tg) |
                         ((unsigned)(a2 >> 32) ^ tg) | ((unsigned)(a3 >> 32) ^ tg);
          if (bad == 0u) break;
          __builtin_amdgcn_s_sleep(1);
        }
        f32x4 v; v.x = lo32(a0); v.y = lo32(a1); v.z = lo32(a2); v.w = lo32(a3);
        *(f32x4*)&rh_s[PHYS(tid * 4)] = v;
      }
      __syncthreads();   // B1
      float aw = 0.f;
      {
        const float* rp = rh_s + q * 68;
#pragma unroll
        for (int i2 = 0; i2 < 16; ++i2) {
          f32x4 rv = *(const f32x4*)(rp + i2 * 4);
          aw = fmaf(uw[i2 * 4 + 0], rv.x, aw); aw = fmaf(uw[i2 * 4 + 1], rv.y, aw);
          aw = fmaf(uw[i2 * 4 + 2], rv.z, aw); aw = fmaf(uw[i2 * 4 + 3], rv.w, aw);
        }
      }
      aw += __shfl_xor(aw, 16, 64); aw += __shfl_xor(aw, 32, 64);
      if (inw < 16) pw[wv][c] = aw;
      __syncthreads();   // B2
      if (tid < 16) {
        float wwv = pw[0][c] + pw[1][c] + pw[2][c] + pw[3][c] + xw + bu;
        float ht = tanhf(wwv);
        float hn = zreg * ht + (1.f - zreg) * hold;
        astore(&g_h1s[(size_t)(s + 1) * 1024 + j], packtv((unsigned)(s + 1), hn));
      }
    }
  } else {
    // ================= layer 2 (input projections fused, weights in regs) =================
    const int g = blockIdx.x - 64;
    const int j = g * 16 + c;
    float uz[64], ur[64], uw[64], wz[64], wr[64], ww[64];
#pragma unroll
    for (int i = 0; i < 64; ++i) uz[i] = Uz2[(size_t)(q * 64 + i) * 1024 + j];
#pragma unroll
    for (int i = 0; i < 64; ++i) ur[i] = Ur2[(size_t)(q * 64 + i) * 1024 + j];
#pragma unroll
    for (int i = 0; i < 64; ++i) uw[i] = Uw2[(size_t)(q * 64 + i) * 1024 + j];
#pragma unroll
    for (int i = 0; i < 64; ++i) wz[i] = Wz2[(size_t)(q * 64 + i) * 1024 + j];
#pragma unroll
    for (int i = 0; i < 64; ++i) wr[i] = Wr2[(size_t)(q * 64 + i) * 1024 + j];
#pragma unroll
    for (int i = 0; i < 64; ++i) ww[i] = Ww2[(size_t)(q * 64 + i) * 1024 + j];
#pragma unroll
    for (int i = 0; i < 64; ++i) {
      KEEPF(uz[i]); KEEPF(ur[i]); KEEPF(uw[i]);
      KEEPF(wz[i]); KEEPF(wr[i]); KEEPF(ww[i]);
    }
    const float bu = bW2[j] + bU2[j];

    float zreg = 0.f, hold = 0.f;
    for (int s = 0; s < 1024; ++s) {
      // ---- poll h2 (tag s) and x = h1 ring slot s+1 (tag s+1) ----
      {
        const unsigned long long* sh = g_h2cur + tid * 4;
        const unsigned long long* sx = g_h1s + (size_t)(s + 1) * 1024 + tid * 4;
        unsigned long long a0, a1, a2, a3, b0, b1, b2, b3;
        const unsigned tg = (unsigned)(s + 1);
        for (;;) {
          a0 = aload(sh); a1 = aload(sh + 1); a2 = aload(sh + 2); a3 = aload(sh + 3);
          b0 = aload(sx); b1 = aload(sx + 1); b2 = aload(sx + 2); b3 = aload(sx + 3);
          unsigned bad = ((unsigned)(a0 >> 32) ^ (unsigned)s) | ((unsigned)(a1 >> 32) ^ (unsigned)s) |
                         ((unsigned)(a2 >> 32) ^ (unsigned)s) | ((unsigned)(a3 >> 32) ^ (unsigned)s) |
                         ((unsigned)(b0 >> 32) ^ tg) | ((unsigned)(b1 >> 32) ^ tg) |
                         ((unsigned)(b2 >> 32) ^ tg) | ((unsigned)(b3 >> 32) ^ tg);
          if (bad == 0u) break;
          __builtin_amdgcn_s_sleep(1);
        }
        f32x4 v; v.x = lo32(a0); v.y = lo32(a1); v.z = lo32(a2); v.w = lo32(a3);
        *(f32x4*)&h_s[PHYS(tid * 4)] = v;
        f32x4 u4; u4.x = lo32(b0); u4.y = lo32(b1); u4.z = lo32(b2); u4.w = lo32(b3);
        *(f32x4*)&x_s[PHYS(tid * 4)] = u4;
      }
      __syncthreads();   // A1
      float az = 0.f, ar = 0.f;
      {
        const float* hp = h_s + q * 68;
        const float* xp = x_s + q * 68;
#pragma unroll
        for (int i2 = 0; i2 < 16; ++i2) {
          f32x4 hv = *(const f32x4*)(hp + i2 * 4);
          f32x4 xv = *(const f32x4*)(xp + i2 * 4);
          az = fmaf(uz[i2 * 4 + 0], hv.x, az); az = fmaf(uz[i2 * 4 + 1], hv.y, az);
          az = fmaf(uz[i2 * 4 + 2], hv.z, az); az = fmaf(uz[i2 * 4 + 3], hv.w, az);
          az = fmaf(wz[i2 * 4 + 0], xv.x, az); az = fmaf(wz[i2 * 4 + 1], xv.y, az);
          az = fmaf(wz[i2 * 4 + 2], xv.z, az); az = fmaf(wz[i2 * 4 + 3], xv.w, az);
          ar = fmaf(ur[i2 * 4 + 0], hv.x, ar); ar = fmaf(ur[i2 * 4 + 1], hv.y, ar);
          ar = fmaf(ur[i2 * 4 + 2], hv.z, ar); ar = fmaf(ur[i2 * 4 + 3], hv.w, ar);
          ar = fmaf(wr[i2 * 4 + 0], xv.x, ar); ar = fmaf(wr[i2 * 4 + 1], xv.y, ar);
          ar = fmaf(wr[i2 * 4 + 2], xv.z, ar); ar = fmaf(wr[i2 * 4 + 3], xv.w, ar);
        }
      }
      az += __shfl_xor(az, 16, 64); az += __shfl_xor(az, 32, 64);
      ar += __shfl_xor(ar, 16, 64); ar += __shfl_xor(ar, 32, 64);
      if (inw < 16) { pz[wv][c] = az; pr[wv][c] = ar; }
      __syncthreads();   // A2
      if (tid < 32) {
        if (tid < 16) {
          float zz = pz[0][c] + pz[1][c] + pz[2][c] + pz[3][c];
          zreg = 1.f / (1.f + __expf(-zz));
          hold = h_s[PHYS(j)];
        } else {
          float rr = pr[0][c] + pr[1][c] + pr[2][c] + pr[3][c];
          float r = 1.f / (1.f + __expf(-rr));
          astore(&g_rh2[j], packtv((unsigned)(s + 1), r * h_s[PHYS(j)]));
        }
      }
      // ---- poll rh2 (tag s+1) ----
      {
        const unsigned long long* sl = g_rh2 + tid * 4;
        unsigned long long a0, a1, a2, a3;
        const unsigned tg = (unsigned)(s + 1);
        for (;;) {
          a0 = aload(sl); a1 = aload(sl + 1); a2 = aload(sl + 2); a3 = aload(sl + 3);
          unsigned bad = ((unsigned)(a0 >> 32) ^ tg) | ((unsigned)(a1 >> 32) ^ tg) |
                         ((unsigned)(a2 >> 32) ^ tg) | ((unsigned)(a3 >> 32) ^ tg);
          if (bad == 0u) break;
          __builtin_amdgcn_s_sleep(1);
        }
        f32x4 v; v.x = lo32(a0); v.y = lo32(a1); v.z = lo32(a2); v.w = lo32(a3);
        *(f32x4*)&rh_s[PHYS(tid * 4)] = v;
      }
      __syncthreads();   // B1
      float aw = 0.f;
      {
        const float* rp = rh_s + q * 68;
        const float* xp = x_s + q * 68;
#pragma unroll
        for (int i2 = 0; i2 < 16; ++i2) {
          f32x4 rv = *(const f32x4*)(rp + i2 * 4);
          f32x4 xv = *(const f32x4*)(xp + i2 * 4);
          aw = fmaf(uw[i2 * 4 + 0], rv.x, aw); aw = fmaf(uw[i2 * 4 + 1], rv.y, aw);
          aw = fmaf(uw[i2 * 4 + 2], rv.z, aw); aw = fmaf(uw[i2 * 4 + 3], rv.w, aw);
          aw = fmaf(ww[i2 * 4 + 0], xv.x, aw); aw = fmaf(ww[i2 * 4 + 1], xv.y, aw);
          aw = fmaf(ww[i2 * 4 + 2], xv.z, aw); aw = fmaf(ww[i2 * 4 + 3], xv.w, aw);
        }
      }
      aw += __shfl_xor(aw, 16, 64); aw += __shfl_xor(aw, 32, 64);
      if (inw < 16) pw[wv][c] = aw;
      __syncthreads();   // B2
      if (tid < 16) {
        float wwv = pw[0][c] + pw[1][c] + pw[2][c] + pw[3][c] + bu;
        float ht = tanhf(wwv);
        float hn = zreg * ht + (1.f - zreg) * hold;
        astore(&g_h2cur[j], packtv((unsigned)(s + 1), hn));
        hs2[(size_t)s * 1024 + j] = hn;
      }
    }
  }
}

// ---------------- bf16 MFMA GEMM: C[M=1024][N] = A(f32,[gather])*B(f32) + bias ----------------
__global__ __launch_bounds__(256, 1) void gemm_mfma(
    const float* __restrict__ A, const int* __restrict__ gidx, int lda,
    const float* __restrict__ B, int ldb,
    const float* __restrict__ bias,
    float* __restrict__ C, int ldc, int N, int K)
{
  __shared__ unsigned short As[128 * GPAD];
  __shared__ unsigned short Bs[128 * GPAD];
  const int tid = threadIdx.x;
  const int lane = tid & 63;
  const int wv = tid >> 6;
  const int wm = wv >> 1, wn = wv & 1;
  const int mbase = blockIdx.y * 128, nbase = blockIdx.x * 128;

  f32x4 acc[4][4];
#pragma unroll
  for (int i = 0; i < 4; ++i)
#pragma unroll
    for (int qq = 0; qq < 4; ++qq) acc[i][qq] = (f32x4){0.f, 0.f, 0.f, 0.f};

  const int ar = tid >> 1, ak = (tid & 1) * 16;
  const float* Arow;
  {
    int m = mbase + ar;
    long long gr = gidx ? (long long)gidx[m] : (long long)m;
    Arow = A + (size_t)gr * (size_t)lda;
  }
  const int bn = (tid >> 3) * 4;
  const int bk = (tid & 7) * 4;
  const bool nedge = (nbase + 128 > N);

  const int ksteps = (K + 31) >> 5;
  for (int ks = 0; ks < ksteps; ++ks) {
    const int k0 = ks << 5;
    __syncthreads();
    {
      float v[16];
      const int kg = k0 + ak;
      if (kg + 16 <= K) {
#pragma unroll
        for (int qq = 0; qq < 4; ++qq) {
          f32x4 t = *(const f32x4*)(Arow + kg + qq * 4);
          v[qq * 4 + 0] = t.x; v[qq * 4 + 1] = t.y; v[qq * 4 + 2] = t.z; v[qq * 4 + 3] = t.w;
        }
      } else {
#pragma unroll
        for (int i = 0; i < 16; ++i) v[i] = (kg + i < K) ? Arow[kg + i] : 0.f;
      }
#pragma unroll
      for (int qq = 0; qq < 4; ++qq) {
        u16x4 wq;
        wq.x = f2bf(v[qq * 4 + 0]); wq.y = f2bf(v[qq * 4 + 1]);
        wq.z = f2bf(v[qq * 4 + 2]); wq.w = f2bf(v[qq * 4 + 3]);
        *(u16x4*)&As[ar * GPAD + ak + qq * 4] = wq;
      }
    }
    {
      float bv[4][4];
#pragma unroll
      for (int kk = 0; kk < 4; ++kk) {
        int kglob = k0 + bk + kk;
        if (kglob < K) {
          if (!nedge) {
            f32x4 t = *(const f32x4*)(B + (size_t)kglob * (size_t)ldb + nbase + bn);
            bv[kk][0] = t.x; bv[kk][1] = t.y; bv[kk][2] = t.z; bv[kk][3] = t.w;
          } else {
#pragma unroll
            for (int nn = 0; nn < 4; ++nn) {
              int n = nbase + bn + nn;
              bv[kk][nn] = (n < N) ? B[(size_t)kglob * (size_t)ldb + n] : 0.f;
            }
          }
        } else {
          bv[kk][0] = bv[kk][1] = bv[kk][2] = bv[kk][3] = 0.f;
        }
      }
#pragma unroll
      for (int nn = 0; nn < 4; ++nn) {
        u16x4 wq;
        wq.x = f2bf(bv[0][nn]); wq.y = f2bf(bv[1][nn]);
        wq.z = f2bf(bv[2][nn]); wq.w = f2bf(bv[3][nn]);
        *(u16x4*)&Bs[(bn + nn) * GPAD + bk] = wq;
      }
    }
    __syncthreads();
    bf16x8 af[4], bfr[4];
    const int fr = lane & 15, fk = (lane >> 4) * 8;
#pragma unroll
    for (int mf = 0; mf < 4; ++mf)
      af[mf] = *(const bf16x8*)&As[(wm * 64 + mf * 16 + fr) * GPAD + fk];
#pragma unroll
    for (int nf = 0; nf < 4; ++nf)
      bfr[nf] = *(const bf16x8*)&Bs[(wn * 64 + nf * 16 + fr) * GPAD + fk];
#pragma unroll
    for (int mf = 0; mf < 4; ++mf)
#pragma unroll
      for (int nf = 0; nf < 4; ++nf)
        acc[mf][nf] = __builtin_amdgcn_mfma_f32_16x16x32_bf16(af[mf], bfr[nf], acc[mf][nf], 0, 0, 0);
  }
  const int fr = lane & 15, fq = lane >> 4;
#pragma unroll
  for (int nf = 0; nf < 4; ++nf) {
    int col = nbase + wn * 64 + nf * 16 + fr;
    if (col < N) {
      float bb = bias ? bias[col] : 0.f;
#pragma unroll
      for (int mf = 0; mf < 4; ++mf) {
        int row0 = mbase + wm * 64 + mf * 16 + fq * 4;
#pragma unroll
        for (int r = 0; r < 4; ++r)
          C[(size_t)(row0 + r) * (size_t)ldc + col] = acc[mf][nf][r] + bb;
      }
    }
  }
}

// ---------------- row-wise log-softmax, in place on d_out ----------------
__global__ __launch_bounds__(256, 1) void logsoftmax_kernel(float* __restrict__ out) {
  const int row = blockIdx.x;
  float* p; int len;
  if (row < 1024) { p = out + (size_t)row * 50000u; len = 50000; }
  else            { p = out + 51200000ull + (size_t)(row - 1024) * 25000u; len = 25000; }
  const int tid = threadIdx.x;
  __shared__ float mred[4], sred[4];

  float m = -3.4e38f;
  for (int i = tid * 4; i < len; i += 1024) {
    f32x4 v = *(const f32x4*)(p + i);
    m = fmaxf(m, fmaxf(fmaxf(v.x, v.y), fmaxf(v.z, v.w)));
  }
#pragma unroll
  for (int off = 32; off >= 1; off >>= 1) m = fmaxf(m, __shfl_xor(m, off, 64));
  if ((tid & 63) == 0) mred[tid >> 6] = m;
  __syncthreads();
  m = fmaxf(fmaxf(mred[0], mred[1]), fmaxf(mred[2], mred[3]));

  float ssum = 0.f;
  for (int i = tid * 4; i < len; i += 1024) {
    f32x4 v = *(const f32x4*)(p + i);
    ssum += __expf(v.x - m) + __expf(v.y - m) + __expf(v.z - m) + __expf(v.w - m);
  }
#pragma unroll
  for (int off = 32; off >= 1; off >>= 1) ssum += __shfl_xor(ssum, off, 64);
  if ((tid & 63) == 0) sred[tid >> 6] = ssum;
  __syncthreads();
  const float lse = m + logf(sred[0] + sred[1] + sred[2] + sred[3]);

  for (int i = tid * 4; i < len; i += 1024) {
    f32x4 v = *(const f32x4*)(p + i);
    v.x -= lse; v.y -= lse; v.z -= lse; v.w -= lse;
    *(f32x4*)(p + i) = v;
  }
}

// ---------------- launch ----------------
extern "C" void kernel_launch(void* const* d_in, const int* in_sizes, int n_in,
                              void* d_out, int out_size, void* d_ws, size_t ws_size,
                              hipStream_t stream) {
  (void)in_sizes; (void)n_in; (void)out_size; (void)d_ws; (void)ws_size;
  const int*   x_idx = (const int*)  d_in[0];
  const float* X     = (const float*)d_in[1];
  const float* W_z_1 = (const float*)d_in[2];
  const float* U_z_1 = (const float*)d_in[3];
  const float* W_r_1 = (const float*)d_in[4];
  const float* U_r_1 = (const float*)d_in[5];
  const float* W_1   = (const float*)d_in[6];
  const float* b_W_1 = (const float*)d_in[7];
  const float* U_1   = (const float*)d_in[8];
  const float* b_U_1 = (const float*)d_in[9];
  const float* W_z_2 = (const float*)d_in[10];
  const float* U_z_2 = (const float*)d_in[11];
  const float* W_r_2 = (const float*)d_in[12];
  const float* U_r_2 = (const float*)d_in[13];
  const float* W_2   = (const float*)d_in[14];
  const float* b_W_2 = (const float*)d_in[15];
  const float* U_2   = (const float*)d_in[16];
  const float* b_U_2 = (const float*)d_in[17];
  const float* W_g   = (const float*)d_in[18];
  const float* b_g   = (const float*)d_in[19];
  const float* W_s   = (const float*)d_in[20];
  const float* b_s   = (const float*)d_in[21];
  float* out = (float*)d_out;

  float *ExW, *hs2;
  unsigned long long* h1s;
  hipGetSymbolAddress((void**)&ExW, HIP_SYMBOL(g_ExW));
  hipGetSymbolAddress((void**)&hs2, HIP_SYMBOL(g_hs2));
  hipGetSymbolAddress((void**)&h1s, HIP_SYMBOL(g_h1s));

  const dim3 blk(256);

  // reset sync state (every launch: graph replays must be self-contained)
  init_kernel<<<dim3(1), dim3(1024), 0, stream>>>();
  hipMemsetAsync(h1s, 0, 1025ull * 1024 * sizeof(unsigned long long), stream);

  // layer-1 input projections: E(=X[idx]) @ {W_z_1, W_r_1, W_1}  -> g_ExW
  gemm_mfma<<<dim3(8, 8), blk, 0, stream>>>(X, x_idx, 300, W_z_1, 1024, nullptr, ExW + 0,    3072, 1024, 300);
  gemm_mfma<<<dim3(8, 8), blk, 0, stream>>>(X, x_idx, 300, W_r_1, 1024, nullptr, ExW + 1024, 3072, 1024, 300);
  gemm_mfma<<<dim3(8, 8), blk, 0, stream>>>(X, x_idx, 300, W_1,   1024, b_W_1,   ExW + 2048, 3072, 1024, 300);

  // fused two-layer pipelined scan (128 WGs x 256 thr)
  fused_scan<<<dim3(128), blk, 0, stream>>>(
      ExW, U_z_1, U_r_1, U_1, b_U_1,
      W_z_2, W_r_2, W_2, U_z_2, U_r_2, U_2, b_W_2, b_U_2, hs2);

  // heads: logits straight into d_out
  gemm_mfma<<<dim3(391, 8), blk, 0, stream>>>(hs2, nullptr, 1024, W_g, 50000, b_g, out,              50000, 50000, 1024);
  gemm_mfma<<<dim3(196, 8), blk, 0, stream>>>(hs2, nullptr, 1024, W_s, 25000, b_s, out + 51200000ll, 25000, 25000, 1024);
  // in-place log-softmax
  logsoftmax_kernel<<<dim3(2048), blk, 0, stream>>>(out);
}

// Round 6
// 6802.753 us; speedup vs baseline: 5.3815x; 1.1814x over previous
//
#include <hip/hip_runtime.h>

typedef __attribute__((ext_vector_type(4))) float f32x4;
typedef __attribute__((ext_vector_type(8))) __bf16 bf16x8;
typedef __attribute__((ext_vector_type(4))) unsigned short u16x4;

#define GPAD 40   // GEMM LDS row pad (ushorts)
#define KEEPF(x) asm volatile("" : "+v"(x))
#define PHYS(i) ((i) + (((i) >> 6) << 2))   // +4 words pad per 64 -> conflict-light b128 slices

// ---------------- persistent scratch ----------------
// Tagged 64-bit words: (step_tag << 32) | f32 bits, agent-scope relaxed atomics (L3-coherent,
// no fences; tag travels with value). g_h1s: write-once ring, slot t = h1 after t steps, tag t.
__device__ unsigned long long g_h1s[1025 * 1024];
__device__ unsigned long long g_rh1[1024];
__device__ unsigned long long g_h2cur[1024];
__device__ unsigned long long g_rh2[1024];
__device__ float g_ExW[1024 * 3072];   // [step][z|r|w] layer-1 input terms
__device__ float g_hs2[1024 * 1024];

__device__ __forceinline__ unsigned short f2bf(float x) {
  unsigned u = __builtin_bit_cast(unsigned, x);
  u += 0x7FFFu + ((u >> 16) & 1u);   // RNE
  return (unsigned short)(u >> 16);
}
__device__ __forceinline__ unsigned long long packtv(unsigned tag, float v) {
  return ((unsigned long long)tag << 32) | (unsigned long long)__builtin_bit_cast(unsigned, v);
}
__device__ __forceinline__ unsigned long long aload(const unsigned long long* p) {
  return __hip_atomic_load(p, __ATOMIC_RELAXED, __HIP_MEMORY_SCOPE_AGENT);
}
__device__ __forceinline__ void astore(unsigned long long* p, unsigned long long v) {
  __hip_atomic_store(p, v, __ATOMIC_RELAXED, __HIP_MEMORY_SCOPE_AGENT);
}
__device__ __forceinline__ float lo32(unsigned long long v) {
  return __builtin_bit_cast(float, (unsigned)v);
}

__global__ void init_kernel() {
  int t = threadIdx.x;
  astore(&g_rh1[t], 0ull);
  astore(&g_h2cur[t], 0ull);
  astore(&g_rh2[t], 0ull);
}

// ---------------- fused 2-layer persistent GRU scan ----------------
// WGs [0,64): layer 1 — 16 cols/WG, wave = 4 cols x 16 slices-of-64; weights 192 f/thread.
// WGs [64,192): layer 2 — 8 cols/WG, wave = 2 cols x 32 slices-of-32; weights 192 f/thread
// (U+W fused). Dot reductions complete IN-WAVE via shfl_xor; only 2 barriers per step.
// z-dot runs inside the rh-poll window (off the critical path).
__global__ __launch_bounds__(256, 1) void fused_scan(
    const float* __restrict__ ExW,
    const float* __restrict__ Uz1, const float* __restrict__ Ur1,
    const float* __restrict__ Uw1, const float* __restrict__ bU1,
    const float* __restrict__ Wz2, const float* __restrict__ Wr2,
    const float* __restrict__ Ww2,
    const float* __restrict__ Uz2, const float* __restrict__ Ur2,
    const float* __restrict__ Uw2,
    const float* __restrict__ bW2, const float* __restrict__ bU2,
    float* __restrict__ hs2)
{
  const int tid = threadIdx.x;
  const int wv = tid >> 6, inw = tid & 63;
  __shared__ __align__(16) float h_s[1088];
  __shared__ __align__(16) float rh_s[1088];
  __shared__ __align__(16) float x_s[1088];

  if (blockIdx.x < 64) {
    // ================= layer 1 =================
    const int g = blockIdx.x;
    const int c2 = inw >> 4, q = inw & 15;     // wave: 4 cols (c2) x 16 slices (q)
    const int j = g * 16 + wv * 4 + c2;
    float uz[64], ur[64], uw[64];
#pragma unroll
    for (int i = 0; i < 64; ++i) uz[i] = Uz1[(size_t)(q * 64 + i) * 1024 + j];
#pragma unroll
    for (int i = 0; i < 64; ++i) ur[i] = Ur1[(size_t)(q * 64 + i) * 1024 + j];
#pragma unroll
    for (int i = 0; i < 64; ++i) uw[i] = Uw1[(size_t)(q * 64 + i) * 1024 + j];
#pragma unroll
    for (int i = 0; i < 64; ++i) { KEEPF(uz[i]); KEEPF(ur[i]); KEEPF(uw[i]); }
    const float bu = bU1[j];

    // ExW terms, prefetched one step ahead (q==0 lanes only)
    float xz = 0.f, xr = 0.f, xw = 0.f;
    if (q == 0) { xz = ExW[j]; xr = ExW[1024 + j]; xw = ExW[2048 + j]; }

    float zreg = 0.f, hold = 0.f;
    for (int s = 0; s < 1024; ++s) {
      // ---- poll h ring slot s (tag s) ----
      {
        const unsigned long long* sl = g_h1s + (size_t)s * 1024 + tid * 4;
        unsigned long long a0, a1, a2, a3;
        for (;;) {
          a0 = aload(sl); a1 = aload(sl + 1); a2 = aload(sl + 2); a3 = aload(sl + 3);
          unsigned bad = ((unsigned)(a0 >> 32) ^ (unsigned)s) | ((unsigned)(a1 >> 32) ^ (unsigned)s) |
                         ((unsigned)(a2 >> 32) ^ (unsigned)s) | ((unsigned)(a3 >> 32) ^ (unsigned)s);
          if (bad == 0u) break;
          __builtin_amdgcn_s_sleep(1);
        }
        f32x4 v; v.x = lo32(a0); v.y = lo32(a1); v.z = lo32(a2); v.w = lo32(a3);
        *(f32x4*)&h_s[PHYS(tid * 4)] = v;
      }
      __syncthreads();   // A
      if (q == 0) hold = h_s[PHYS(j)];
      // ---- r-dot (critical) ----
      float ar_ = 0.f;
      {
        const float* hp = h_s + q * 68;
#pragma unroll
        for (int i2 = 0; i2 < 16; ++i2) {
          f32x4 hv = *(const f32x4*)(hp + i2 * 4);
          ar_ = fmaf(ur[i2 * 4 + 0], hv.x, ar_); ar_ = fmaf(ur[i2 * 4 + 1], hv.y, ar_);
          ar_ = fmaf(ur[i2 * 4 + 2], hv.z, ar_); ar_ = fmaf(ur[i2 * 4 + 3], hv.w, ar_);
        }
      }
      ar_ += __shfl_xor(ar_, 1, 64); ar_ += __shfl_xor(ar_, 2, 64);
      ar_ += __shfl_xor(ar_, 4, 64); ar_ += __shfl_xor(ar_, 8, 64);
      if (q == 0) {
        float r = 1.f / (1.f + __expf(-(ar_ + xr)));
        astore(&g_rh1[j], packtv((unsigned)(s + 1), r * hold));
      }
      // ---- z-dot + ExW prefetch inside the rh-poll window ----
      float az_ = 0.f;
      {
        const float* hp = h_s + q * 68;
#pragma unroll
        for (int i2 = 0; i2 < 16; ++i2) {
          f32x4 hv = *(const f32x4*)(hp + i2 * 4);
          az_ = fmaf(uz[i2 * 4 + 0], hv.x, az_); az_ = fmaf(uz[i2 * 4 + 1], hv.y, az_);
          az_ = fmaf(uz[i2 * 4 + 2], hv.z, az_); az_ = fmaf(uz[i2 * 4 + 3], hv.w, az_);
        }
      }
      az_ += __shfl_xor(az_, 1, 64); az_ += __shfl_xor(az_, 2, 64);
      az_ += __shfl_xor(az_, 4, 64); az_ += __shfl_xor(az_, 8, 64);
      if (q == 0) zreg = 1.f / (1.f + __expf(-(az_ + xz)));
      float nxz = 0.f, nxr = 0.f, nxw = 0.f;
      if (q == 0 && s < 1023) {
        nxz = ExW[(s + 1) * 3072 + j];
        nxr = ExW[(s + 1) * 3072 + 1024 + j];
        nxw = ExW[(s + 1) * 3072 + 2048 + j];
      }
      // ---- poll rh (tag s+1) ----
      {
        const unsigned long long* sl = g_rh1 + tid * 4;
        unsigned long long a0, a1, a2, a3;
        const unsigned tg = (unsigned)(s + 1);
        for (;;) {
          a0 = aload(sl); a1 = aload(sl + 1); a2 = aload(sl + 2); a3 = aload(sl + 3);
          unsigned bad = ((unsigned)(a0 >> 32) ^ tg) | ((unsigned)(a1 >> 32) ^ tg) |
                         ((unsigned)(a2 >> 32) ^ tg) | ((unsigned)(a3 >> 32) ^ tg);
          if (bad == 0u) break;
          __builtin_amdgcn_s_sleep(1);
        }
        f32x4 v; v.x = lo32(a0); v.y = lo32(a1); v.z = lo32(a2); v.w = lo32(a3);
        *(f32x4*)&rh_s[PHYS(tid * 4)] = v;
      }
      __syncthreads();   // B
      float aw_ = 0.f;
      {
        const float* rp = rh_s + q * 68;
#pragma unroll
        for (int i2 = 0; i2 < 16; ++i2) {
          f32x4 rv = *(const f32x4*)(rp + i2 * 4);
          aw_ = fmaf(uw[i2 * 4 + 0], rv.x, aw_); aw_ = fmaf(uw[i2 * 4 + 1], rv.y, aw_);
          aw_ = fmaf(uw[i2 * 4 + 2], rv.z, aw_); aw_ = fmaf(uw[i2 * 4 + 3], rv.w, aw_);
        }
      }
      aw_ += __shfl_xor(aw_, 1, 64); aw_ += __shfl_xor(aw_, 2, 64);
      aw_ += __shfl_xor(aw_, 4, 64); aw_ += __shfl_xor(aw_, 8, 64);
      if (q == 0) {
        float ht = tanhf(aw_ + xw + bu);
        float hn = zreg * ht + (1.f - zreg) * hold;
        astore(&g_h1s[(size_t)(s + 1) * 1024 + j], packtv((unsigned)(s + 1), hn));
      }
      xz = nxz; xr = nxr; xw = nxw;
    }
  } else {
    // ================= layer 2 (128 WGs; U+W fused; weights fully in regs) =================
    const int g = blockIdx.x - 64;
    const int c2 = inw >> 5, q = inw & 31;     // wave: 2 cols (c2) x 32 slices (q)
    const int j = g * 8 + wv * 2 + c2;
    const int sb = q * 32 + ((q >> 1) << 2);   // PHYS base of this thread's 32-slice
    float uz[32], ur[32], uw[32], wz[32], wr[32], ww[32];
#pragma unroll
    for (int i = 0; i < 32; ++i) uz[i] = Uz2[(size_t)(q * 32 + i) * 1024 + j];
#pragma unroll
    for (int i = 0; i < 32; ++i) ur[i] = Ur2[(size_t)(q * 32 + i) * 1024 + j];
#pragma unroll
    for (int i = 0; i < 32; ++i) uw[i] = Uw2[(size_t)(q * 32 + i) * 1024 + j];
#pragma unroll
    for (int i = 0; i < 32; ++i) wz[i] = Wz2[(size_t)(q * 32 + i) * 1024 + j];
#pragma unroll
    for (int i = 0; i < 32; ++i) wr[i] = Wr2[(size_t)(q * 32 + i) * 1024 + j];
#pragma unroll
    for (int i = 0; i < 32; ++i) ww[i] = Ww2[(size_t)(q * 32 + i) * 1024 + j];
#pragma unroll
    for (int i = 0; i < 32; ++i) {
      KEEPF(uz[i]); KEEPF(ur[i]); KEEPF(uw[i]);
      KEEPF(wz[i]); KEEPF(wr[i]); KEEPF(ww[i]);
    }
    const float bu = bW2[j] + bU2[j];

    float zreg = 0.f, hold = 0.f;
    for (int s = 0; s < 1024; ++s) {
      // ---- poll h2 (tag s) and x = h1 ring slot s+1 (tag s+1) ----
      {
        const unsigned long long* sh = g_h2cur + tid * 4;
        const unsigned long long* sx = g_h1s + (size_t)(s + 1) * 1024 + tid * 4;
        unsigned long long a0, a1, a2, a3, b0, b1, b2, b3;
        const unsigned tg = (unsigned)(s + 1);
        for (;;) {
          a0 = aload(sh); a1 = aload(sh + 1); a2 = aload(sh + 2); a3 = aload(sh + 3);
          b0 = aload(sx); b1 = aload(sx + 1); b2 = aload(sx + 2); b3 = aload(sx + 3);
          unsigned bad = ((unsigned)(a0 >> 32) ^ (unsigned)s) | ((unsigned)(a1 >> 32) ^ (unsigned)s) |
                         ((unsigned)(a2 >> 32) ^ (unsigned)s) | ((unsigned)(a3 >> 32) ^ (unsigned)s) |
                         ((unsigned)(b0 >> 32) ^ tg) | ((unsigned)(b1 >> 32) ^ tg) |
                         ((unsigned)(b2 >> 32) ^ tg) | ((unsigned)(b3 >> 32) ^ tg);
          if (bad == 0u) break;
          __builtin_amdgcn_s_sleep(1);
        }
        f32x4 v; v.x = lo32(a0); v.y = lo32(a1); v.z = lo32(a2); v.w = lo32(a3);
        *(f32x4*)&h_s[PHYS(tid * 4)] = v;
        f32x4 u4; u4.x = lo32(b0); u4.y = lo32(b1); u4.z = lo32(b2); u4.w = lo32(b3);
        *(f32x4*)&x_s[PHYS(tid * 4)] = u4;
      }
      __syncthreads();   // A
      if (q == 0) hold = h_s[PHYS(j)];
      // ---- r-dot (critical): U_r*h + W_r*x ----
      float ar_ = 0.f;
      {
        const float* hp = h_s + sb;
        const float* xp = x_s + sb;
#pragma unroll
        for (int i2 = 0; i2 < 8; ++i2) {
          f32x4 hv = *(const f32x4*)(hp + i2 * 4);
          f32x4 xv = *(const f32x4*)(xp + i2 * 4);
          ar_ = fmaf(ur[i2 * 4 + 0], hv.x, ar_); ar_ = fmaf(ur[i2 * 4 + 1], hv.y, ar_);
          ar_ = fmaf(ur[i2 * 4 + 2], hv.z, ar_); ar_ = fmaf(ur[i2 * 4 + 3], hv.w, ar_);
          ar_ = fmaf(wr[i2 * 4 + 0], xv.x, ar_); ar_ = fmaf(wr[i2 * 4 + 1], xv.y, ar_);
          ar_ = fmaf(wr[i2 * 4 + 2], xv.z, ar_); ar_ = fmaf(wr[i2 * 4 + 3], xv.w, ar_);
        }
      }
      ar_ += __shfl_xor(ar_, 1, 64); ar_ += __shfl_xor(ar_, 2, 64);
      ar_ += __shfl_xor(ar_, 4, 64); ar_ += __shfl_xor(ar_, 8, 64);
      ar_ += __shfl_xor(ar_, 16, 64);
      if (q == 0) {
        float r = 1.f / (1.f + __expf(-ar_));
        astore(&g_rh2[j], packtv((unsigned)(s + 1), r * hold));
      }
      // ---- z-dot inside the rh-poll window ----
      float az_ = 0.f;
      {
        const float* hp = h_s + sb;
        const float* xp = x_s + sb;
#pragma unroll
        for (int i2 = 0; i2 < 8; ++i2) {
          f32x4 hv = *(const f32x4*)(hp + i2 * 4);
          f32x4 xv = *(const f32x4*)(xp + i2 * 4);
          az_ = fmaf(uz[i2 * 4 + 0], hv.x, az_); az_ = fmaf(uz[i2 * 4 + 1], hv.y, az_);
          az_ = fmaf(uz[i2 * 4 + 2], hv.z, az_); az_ = fmaf(uz[i2 * 4 + 3], hv.w, az_);
          az_ = fmaf(wz[i2 * 4 + 0], xv.x, az_); az_ = fmaf(wz[i2 * 4 + 1], xv.y, az_);
          az_ = fmaf(wz[i2 * 4 + 2], xv.z, az_); az_ = fmaf(wz[i2 * 4 + 3], xv.w, az_);
        }
      }
      az_ += __shfl_xor(az_, 1, 64); az_ += __shfl_xor(az_, 2, 64);
      az_ += __shfl_xor(az_, 4, 64); az_ += __shfl_xor(az_, 8, 64);
      az_ += __shfl_xor(az_, 16, 64);
      if (q == 0) zreg = 1.f / (1.f + __expf(-az_));
      // ---- poll rh2 (tag s+1) ----
      {
        const unsigned long long* sl = g_rh2 + tid * 4;
        unsigned long long a0, a1, a2, a3;
        const unsigned tg = (unsigned)(s + 1);
        for (;;) {
          a0 = aload(sl); a1 = aload(sl + 1); a2 = aload(sl + 2); a3 = aload(sl + 3);
          unsigned bad = ((unsigned)(a0 >> 32) ^ tg) | ((unsigned)(a1 >> 32) ^ tg) |
                         ((unsigned)(a2 >> 32) ^ tg) | ((unsigned)(a3 >> 32) ^ tg);
          if (bad == 0u) break;
          __builtin_amdgcn_s_sleep(1);
        }
        f32x4 v; v.x = lo32(a0); v.y = lo32(a1); v.z = lo32(a2); v.w = lo32(a3);
        *(f32x4*)&rh_s[PHYS(tid * 4)] = v;
      }
      __syncthreads();   // B
      float aw_ = 0.f;
      {
        const float* rp = rh_s + sb;
        const float* xp = x_s + sb;
#pragma unroll
        for (int i2 = 0; i2 < 8; ++i2) {
          f32x4 rv = *(const f32x4*)(rp + i2 * 4);
          f32x4 xv = *(const f32x4*)(xp + i2 * 4);
          aw_ = fmaf(uw[i2 * 4 + 0], rv.x, aw_); aw_ = fmaf(uw[i2 * 4 + 1], rv.y, aw_);
          aw_ = fmaf(uw[i2 * 4 + 2], rv.z, aw_); aw_ = fmaf(uw[i2 * 4 + 3], rv.w, aw_);
          aw_ = fmaf(ww[i2 * 4 + 0], xv.x, aw_); aw_ = fmaf(ww[i2 * 4 + 1], xv.y, aw_);
          aw_ = fmaf(ww[i2 * 4 + 2], xv.z, aw_); aw_ = fmaf(ww[i2 * 4 + 3], xv.w, aw_);
        }
      }
      aw_ += __shfl_xor(aw_, 1, 64); aw_ += __shfl_xor(aw_, 2, 64);
      aw_ += __shfl_xor(aw_, 4, 64); aw_ += __shfl_xor(aw_, 8, 64);
      aw_ += __shfl_xor(aw_, 16, 64);
      if (q == 0) {
        float ht = tanhf(aw_ + bu);
        float hn = zreg * ht + (1.f - zreg) * hold;
        astore(&g_h2cur[j], packtv((unsigned)(s + 1), hn));
        hs2[(size_t)s * 1024 + j] = hn;
      }
    }
  }
}

// ---------------- bf16 MFMA GEMM: C[M=1024][N] = A(f32,[gather])*B(f32) + bias ----------------
__global__ __launch_bounds__(256, 1) void gemm_mfma(
    const float* __restrict__ A, const int* __restrict__ gidx, int lda,
    const float* __restrict__ B, int ldb,
    const float* __restrict__ bias,
    float* __restrict__ C, int ldc, int N, int K)
{
  __shared__ unsigned short As[128 * GPAD];
  __shared__ unsigned short Bs[128 * GPAD];
  const int tid = threadIdx.x;
  const int lane = tid & 63;
  const int wv = tid >> 6;
  const int wm = wv >> 1, wn = wv & 1;
  const int mbase = blockIdx.y * 128, nbase = blockIdx.x * 128;

  f32x4 acc[4][4];
#pragma unroll
  for (int i = 0; i < 4; ++i)
#pragma unroll
    for (int qq = 0; qq < 4; ++qq) acc[i][qq] = (f32x4){0.f, 0.f, 0.f, 0.f};

  const int ar = tid >> 1, ak = (tid & 1) * 16;
  const float* Arow;
  {
    int m = mbase + ar;
    long long gr = gidx ? (long long)gidx[m] : (long long)m;
    Arow = A + (size_t)gr * (size_t)lda;
  }
  const int bn = (tid >> 3) * 4;
  const int bk = (tid & 7) * 4;
  const bool nedge = (nbase + 128 > N);

  const int ksteps = (K + 31) >> 5;
  for (int ks = 0; ks < ksteps; ++ks) {
    const int k0 = ks << 5;
    __syncthreads();
    {
      float v[16];
      const int kg = k0 + ak;
      if (kg + 16 <= K) {
#pragma unroll
        for (int qq = 0; qq < 4; ++qq) {
          f32x4 t = *(const f32x4*)(Arow + kg + qq * 4);
          v[qq * 4 + 0] = t.x; v[qq * 4 + 1] = t.y; v[qq * 4 + 2] = t.z; v[qq * 4 + 3] = t.w;
        }
      } else {
#pragma unroll
        for (int i = 0; i < 16; ++i) v[i] = (kg + i < K) ? Arow[kg + i] : 0.f;
      }
#pragma unroll
      for (int qq = 0; qq < 4; ++qq) {
        u16x4 wq;
        wq.x = f2bf(v[qq * 4 + 0]); wq.y = f2bf(v[qq * 4 + 1]);
        wq.z = f2bf(v[qq * 4 + 2]); wq.w = f2bf(v[qq * 4 + 3]);
        *(u16x4*)&As[ar * GPAD + ak + qq * 4] = wq;
      }
    }
    {
      float bv[4][4];
#pragma unroll
      for (int kk = 0; kk < 4; ++kk) {
        int kglob = k0 + bk + kk;
        if (kglob < K) {
          if (!nedge) {
            f32x4 t = *(const f32x4*)(B + (size_t)kglob * (size_t)ldb + nbase + bn);
            bv[kk][0] = t.x; bv[kk][1] = t.y; bv[kk][2] = t.z; bv[kk][3] = t.w;
          } else {
#pragma unroll
            for (int nn = 0; nn < 4; ++nn) {
              int n = nbase + bn + nn;
              bv[kk][nn] = (n < N) ? B[(size_t)kglob * (size_t)ldb + n] : 0.f;
            }
          }
        } else {
          bv[kk][0] = bv[kk][1] = bv[kk][2] = bv[kk][3] = 0.f;
        }
      }
#pragma unroll
      for (int nn = 0; nn < 4; ++nn) {
        u16x4 wq;
        wq.x = f2bf(bv[0][nn]); wq.y = f2bf(bv[1][nn]);
        wq.z = f2bf(bv[2][nn]); wq.w = f2bf(bv[3][nn]);
        *(u16x4*)&Bs[(bn + nn) * GPAD + bk] = wq;
      }
    }
    __syncthreads();
    bf16x8 af[4], bfr[4];
    const int fr = lane & 15, fk = (lane >> 4) * 8;
#pragma unroll
    for (int mf = 0; mf < 4; ++mf)
      af[mf] = *(const bf16x8*)&As[(wm * 64 + mf * 16 + fr) * GPAD + fk];
#pragma unroll
    for (int nf = 0; nf < 4; ++nf)
      bfr[nf] = *(const bf16x8*)&Bs[(wn * 64 + nf * 16 + fr) * GPAD + fk];
#pragma unroll
    for (int mf = 0; mf < 4; ++mf)
#pragma unroll
      for (int nf = 0; nf < 4; ++nf)
        acc[mf][nf] = __builtin_amdgcn_mfma_f32_16x16x32_bf16(af[mf], bfr[nf], acc[mf][nf], 0, 0, 0);
  }
  const int fr = lane & 15, fq = lane >> 4;
#pragma unroll
  for (int nf = 0; nf < 4; ++nf) {
    int col = nbase + wn * 64 + nf * 16 + fr;
    if (col < N) {
      float bb = bias ? bias[col] : 0.f;
#pragma unroll
      for (int mf = 0; mf < 4; ++mf) {
        int row0 = mbase + wm * 64 + mf * 16 + fq * 4;
#pragma unroll
        for (int r = 0; r < 4; ++r)
          C[(size_t)(row0 + r) * (size_t)ldc + col] = acc[mf][nf][r] + bb;
      }
    }
  }
}

// ---------------- row-wise log-softmax, in place on d_out ----------------
__global__ __launch_bounds__(256, 1) void logsoftmax_kernel(float* __restrict__ out) {
  const int row = blockIdx.x;
  float* p; int len;
  if (row < 1024) { p = out + (size_t)row * 50000u; len = 50000; }
  else            { p = out + 51200000ull + (size_t)(row - 1024) * 25000u; len = 25000; }
  const int tid = threadIdx.x;
  __shared__ float mred[4], sred[4];

  float m = -3.4e38f;
  for (int i = tid * 4; i < len; i += 1024) {
    f32x4 v = *(const f32x4*)(p + i);
    m = fmaxf(m, fmaxf(fmaxf(v.x, v.y), fmaxf(v.z, v.w)));
  }
#pragma unroll
  for (int off = 32; off >= 1; off >>= 1) m = fmaxf(m, __shfl_xor(m, off, 64));
  if ((tid & 63) == 0) mred[tid >> 6] = m;
  __syncthreads();
  m = fmaxf(fmaxf(mred[0], mred[1]), fmaxf(mred[2], mred[3]));

  float ssum = 0.f;
  for (int i = tid * 4; i < len; i += 1024) {
    f32x4 v = *(const f32x4*)(p + i);
    ssum += __expf(v.x - m) + __expf(v.y - m) + __expf(v.z - m) + __expf(v.w - m);
  }
#pragma unroll
  for (int off = 32; off >= 1; off >>= 1) ssum += __shfl_xor(ssum, off, 64);
  if ((tid & 63) == 0) sred[tid >> 6] = ssum;
  __syncthreads();
  const float lse = m + logf(sred[0] + sred[1] + sred[2] + sred[3]);

  for (int i = tid * 4; i < len; i += 1024) {
    f32x4 v = *(const f32x4*)(p + i);
    v.x -= lse; v.y -= lse; v.z -= lse; v.w -= lse;
    *(f32x4*)(p + i) = v;
  }
}

// ---------------- launch ----------------
extern "C" void kernel_launch(void* const* d_in, const int* in_sizes, int n_in,
                              void* d_out, int out_size, void* d_ws, size_t ws_size,
                              hipStream_t stream) {
  (void)in_sizes; (void)n_in; (void)out_size; (void)d_ws; (void)ws_size;
  const int*   x_idx = (const int*)  d_in[0];
  const float* X     = (const float*)d_in[1];
  const float* W_z_1 = (const float*)d_in[2];
  const float* U_z_1 = (const float*)d_in[3];
  const float* W_r_1 = (const float*)d_in[4];
  const float* U_r_1 = (const float*)d_in[5];
  const float* W_1   = (const float*)d_in[6];
  const float* b_W_1 = (const float*)d_in[7];
  const float* U_1   = (const float*)d_in[8];
  const float* b_U_1 = (const float*)d_in[9];
  const float* W_z_2 = (const float*)d_in[10];
  const float* U_z_2 = (const float*)d_in[11];
  const float* W_r_2 = (const float*)d_in[12];
  const float* U_r_2 = (const float*)d_in[13];
  const float* W_2   = (const float*)d_in[14];
  const float* b_W_2 = (const float*)d_in[15];
  const float* U_2   = (const float*)d_in[16];
  const float* b_U_2 = (const float*)d_in[17];
  const float* W_g   = (const float*)d_in[18];
  const float* b_g   = (const float*)d_in[19];
  const float* W_s   = (const float*)d_in[20];
  const float* b_s   = (const float*)d_in[21];
  float* out = (float*)d_out;

  float *ExW, *hs2;
  unsigned long long* h1s;
  hipGetSymbolAddress((void**)&ExW, HIP_SYMBOL(g_ExW));
  hipGetSymbolAddress((void**)&hs2, HIP_SYMBOL(g_hs2));
  hipGetSymbolAddress((void**)&h1s, HIP_SYMBOL(g_h1s));

  const dim3 blk(256);

  // reset sync state (every launch: graph replays must be self-contained)
  init_kernel<<<dim3(1), dim3(1024), 0, stream>>>();
  hipMemsetAsync(h1s, 0, 1025ull * 1024 * sizeof(unsigned long long), stream);

  // layer-1 input projections: E(=X[idx]) @ {W_z_1, W_r_1, W_1}  -> g_ExW
  gemm_mfma<<<dim3(8, 8), blk, 0, stream>>>(X, x_idx, 300, W_z_1, 1024, nullptr, ExW + 0,    3072, 1024, 300);
  gemm_mfma<<<dim3(8, 8), blk, 0, stream>>>(X, x_idx, 300, W_r_1, 1024, nullptr, ExW + 1024, 3072, 1024, 300);
  gemm_mfma<<<dim3(8, 8), blk, 0, stream>>>(X, x_idx, 300, W_1,   1024, b_W_1,   ExW + 2048, 3072, 1024, 300);

  // fused two-layer pipelined scan (64 L1-WGs + 128 L2-WGs, 256 thr each)
  fused_scan<<<dim3(192), blk, 0, stream>>>(
      ExW, U_z_1, U_r_1, U_1, b_U_1,
      W_z_2, W_r_2, W_2, U_z_2, U_r_2, U_2, b_W_2, b_U_2, hs2);

  // heads: logits straight into d_out
  gemm_mfma<<<dim3(391, 8), blk, 0, stream>>>(hs2, nullptr, 1024, W_g, 50000, b_g, out,              50000, 50000, 1024);
  gemm_mfma<<<dim3(196, 8), blk, 0, stream>>>(hs2, nullptr, 1024, W_s, 25000, b_s, out + 51200000ll, 25000, 25000, 1024);
  // in-place log-softmax
  logsoftmax_kernel<<<dim3(2048), blk, 0, stream>>>(out);
}